// Round 5
// baseline (197.862 us; speedup 1.0000x reference)
//
#include <hip/hip_runtime.h>
#include <stdint.h>
#include <stddef.h>

// Problem constants
#define NB   16
#define NC   64
#define NH   64
#define NW   64
#define KC   16
#define NOUT 64
#define NRANK 8
#define NMLP 32
#define NF   576      // C*3*3
#define NPIX 4096     // H*W
#define XH   66       // halo height/width for channel-last copy

typedef short s16x8 __attribute__((ext_vector_type(8)));
typedef short s16x4 __attribute__((ext_vector_type(4)));
typedef float f32x4 __attribute__((ext_vector_type(4)));

__device__ __forceinline__ unsigned short f2bf(float x) {
    union { float f; uint32_t u; } v; v.f = x;
    uint32_t r = v.u + 0x7FFFu + ((v.u >> 16) & 1u);   // RTNE
    return (unsigned short)(r >> 16);
}
__device__ __forceinline__ float bf2f(unsigned short u) {
    union { uint32_t u; float f; } v; v.u = ((uint32_t)u) << 16;
    return v.f;
}

// ---------------------------------------------------------------------------
// k_prep: x [B][C][H][W] f32 -> xcl [B][66][66][64] bf16 channel-last with a
// zero halo. Coalesced via LDS transpose. grid = 66*16 (yy*16 + b), 256 thr.
// ---------------------------------------------------------------------------
extern "C" __global__ __launch_bounds__(256)
void k_prep(const float* __restrict__ x, unsigned short* __restrict__ xcl)
{
    const int blk = blockIdx.x;
    const int b = blk & 15, yy = blk >> 4;
    const int tid = threadIdx.x;
    unsigned short* dst = xcl + ((size_t)(b * XH + yy) * XH) * 64;
    if (yy == 0 || yy == XH - 1) {
        for (int e = tid; e < XH * 64; e += 256) dst[e] = 0;
        return;
    }
    __shared__ float tile[64 * 65];
    const int y = yy - 1;
    const float* src = x + (size_t)b * NC * (NH * NW) + y * NW;
    #pragma unroll
    for (int rr = 0; rr < 16; ++rr) {
        int c = rr * 4 + (tid >> 6);
        int xx = tid & 63;
        tile[c * 65 + xx] = src[(size_t)c * (NH * NW) + xx];
    }
    __syncthreads();
    for (int e = tid; e < XH * 64; e += 256) {
        int xx = e >> 6, c = e & 63;
        float v = (xx == 0 || xx == XH - 1) ? 0.f : tile[c * 65 + (xx - 1)];
        dst[e] = f2bf(v);
    }
}

// ---------------------------------------------------------------------------
// k_prepT: basek [R][F][O] (F = c*9+tap) -> basekF bf16 in the exact per-lane
// order k_main's W-build consumes:
//   basekF[(((ks*4 + wv)*8 + r)*64 + lane)*8 + j]
//     = basek[r][ c*9 + tap ][ col ]  where col = wv*16 + (lane&15),
//       f' = (lane>>4)*8 + ks*32 + j, tap = f'>>6, c = f'&63.
// => each wave W-build load is 1024B contiguous (fully coalesced).
// grid = 72 (ks*4 + wv), 256 thr; each thread writes 16 consecutive u16.
// ---------------------------------------------------------------------------
extern "C" __global__ __launch_bounds__(256)
void k_prepT(const float* __restrict__ basek, unsigned short* __restrict__ basekF)
{
    const int blk = blockIdx.x;            // ks*4 + wv
    const int ks = blk >> 2, wv = blk & 3;
    const int tid = threadIdx.x;
    unsigned short outv[16];
    #pragma unroll
    for (int i = 0; i < 16; ++i) {
        int e = tid * 16 + i;              // e = r*512 + lane*8 + j
        int r = e >> 9;
        int lane = (e >> 3) & 63;
        int j = e & 7;
        int col = wv * 16 + (lane & 15);
        int fp = (lane >> 4) * 8 + ks * 32 + j;
        int tap = fp >> 6, c = fp & 63;
        outv[i] = f2bf(basek[((size_t)r * NF + c * 9 + tap) * NOUT + col]);
    }
    unsigned short* dst = basekF + (size_t)blk * 4096 + tid * 16;
    #pragma unroll
    for (int i = 0; i < 16; ++i) dst[i] = outv[i];
}

// ---------------------------------------------------------------------------
// k_centers: per-(b,k) order-preserving pixel list + slot map + counts +
// cluster centers (coalesced gathers from L2-resident xcl: wave=tap, lane=c).
// grid 256 (k*16+b), 576 thr.
// ---------------------------------------------------------------------------
extern "C" __global__ __launch_bounds__(576)
void k_centers(const unsigned short* __restrict__ xcl, const int* __restrict__ labels,
               unsigned short* __restrict__ lists, unsigned short* __restrict__ slotmap,
               int* __restrict__ counts, float* __restrict__ centers)
{
    const int bk = blockIdx.x;
    const int b = bk & 15, k = bk >> 4;
    __shared__ unsigned short list[NPIX];   // 8 KB
    __shared__ int wcnt[9];
    const int tid = threadIdx.x;
    const int lane = tid & 63, wv = tid >> 6;
    const int* lab = labels + b * NPIX;

    int total = 0;
    for (int base = 0; base < NPIX; base += 576) {
        int n = base + tid;
        bool pred = (n < NPIX) && (lab[n] == k);
        unsigned long long m = __ballot(pred);
        if (lane == 0) wcnt[wv] = __popcll(m);
        int pre = __popcll(m & ((1ull << lane) - 1ull));
        __syncthreads();
        int wbase = total;
        for (int i = 0; i < wv; ++i) wbase += wcnt[i];
        int nt = total;
        for (int i = 0; i < 9; ++i) nt += wcnt[i];
        if (pred) {
            int slot = wbase + pre;
            list[slot] = (unsigned short)n;
            slotmap[b * NPIX + n] = (unsigned short)slot;
        }
        total = nt;
        __syncthreads();
    }
    const int cnt = total;
    unsigned short* gl = lists + bk * NPIX;
    for (int i = tid; i < cnt; i += 576) gl[i] = list[i];
    if (tid == 0) counts[bk] = cnt;

    // segmented mean gather: wave wv = tap, lane = c
    const int tap = wv;
    const int c = lane;
    const int dy = tap / 3, dx = tap - dy * 3;       // halo offsets 0..2
    const unsigned short* xb = xcl + (size_t)b * (XH * XH * 64);
    float s0 = 0.f, s1 = 0.f;
    int i = 0;
    #pragma unroll 4
    for (; i + 1 < cnt; i += 2) {
        int n0 = list[i], n1 = list[i + 1];
        s0 += bf2f(xb[((((n0 >> 6) + dy) * XH) + (n0 & 63) + dx) * 64 + c]);
        s1 += bf2f(xb[((((n1 >> 6) + dy) * XH) + (n1 & 63) + dx) * 64 + c]);
    }
    if (i < cnt) {
        int n0 = list[i];
        s0 += bf2f(xb[((((n0 >> 6) + dy) * XH) + (n0 & 63) + dx) * 64 + c]);
    }
    centers[bk * NF + c * 9 + tap] = (s0 + s1) / ((float)cnt + 1e-6f);
}

// ---------------------------------------------------------------------------
// k_expand: MLPs on centers (fp32) -> lr[bk][8], biasrows[bk][64], and
// prefixes[bk] (exclusive prefix of counts over k for each b).
// ---------------------------------------------------------------------------
extern "C" __global__ __launch_bounds__(256)
void k_expand(const float* __restrict__ centers, const int* __restrict__ counts,
              const float* __restrict__ lw1, const float* __restrict__ lb1,
              const float* __restrict__ lw2, const float* __restrict__ lb2,
              const float* __restrict__ lw3, const float* __restrict__ lb3,
              const float* __restrict__ bw1, const float* __restrict__ bb1,
              const float* __restrict__ bw2, const float* __restrict__ bb2,
              float* __restrict__ lrout, float* __restrict__ biasrows,
              int* __restrict__ prefixes)
{
    const int bk = blockIdx.x;
    const int b = bk & 15, k = bk >> 4;
    const int tid = threadIdx.x;
    __shared__ float c[NF];
    __shared__ float p1[8][NMLP], pb[8][NMLP];
    __shared__ float h1[NMLP], h2[NMLP], hb[NMLP];

    for (int i = tid; i < NF; i += 256) c[i] = centers[bk * NF + i];
    if (tid == 224) {
        int s = 0;
        for (int kk = 0; kk < k; ++kk) s += counts[kk * 16 + b];
        prefixes[bk] = s;
    }
    __syncthreads();

    {   // layer-1 of both MLPs
        const int j = tid & 31, ch = tid >> 5;       // 8 chunks x 72 feats
        float a1 = 0.f, a2 = 0.f;
        for (int i = 0; i < 72; ++i) {
            int f = ch * 72 + i;
            float cv = c[f];
            a1 += cv * lw1[f * NMLP + j];
            a2 += cv * bw1[f * NMLP + j];
        }
        p1[ch][j] = a1; pb[ch][j] = a2;
    }
    __syncthreads();
    if (tid < NMLP) {
        float a = lb1[tid];
        for (int i = 0; i < 8; ++i) a += p1[i][tid];
        h1[tid] = fmaxf(a, 0.f);
    } else if (tid < 2 * NMLP) {
        int j = tid - NMLP;
        float a = bb1[j];
        for (int i = 0; i < 8; ++i) a += pb[i][j];
        hb[j] = fmaxf(a, 0.f);
    }
    __syncthreads();
    if (tid < NMLP) {
        float a = lb2[tid];
        for (int i = 0; i < NMLP; ++i) a += h1[i] * lw2[i * NMLP + tid];
        h2[tid] = fmaxf(a, 0.f);
    } else if (tid >= 64 && tid < 128) {
        int o = tid - 64;
        float a = bb2[o];
        for (int i = 0; i < NMLP; ++i) a += hb[i] * bw2[i * NOUT + o];
        biasrows[bk * NOUT + o] = a;
    }
    __syncthreads();
    if (tid < NRANK) {
        float a = lb3[tid];
        for (int i = 0; i < NMLP; ++i) a += h2[i] * lw3[i * NRANK + tid];
        lrout[bk * NRANK + tid] = a;
    }
}

// ---------------------------------------------------------------------------
// k_main: gathered GEMM. grid 1024 = 4 splits x 256 (b,k); 256 thr.
// __launch_bounds__(256,4): 4 blocks/CU (LDS 37.6KB, VGPR<=128) for TLP.
// W-build: coalesced basekF loads (1024B/wave-instr), fragments in registers.
// NO register prefetch across barriers (round-4 spill lesson): staging regs
// are short-lived load->ds_write.
// Output compact bf16 outc[b][prefix+slot][o].
// ---------------------------------------------------------------------------
extern "C" __global__ __launch_bounds__(256, 4)
void k_main(const unsigned short* __restrict__ xcl, const unsigned short* __restrict__ lists,
            const int* __restrict__ counts, const unsigned short* __restrict__ basekF,
            const float* __restrict__ lr, const float* __restrict__ biasrows,
            const int* __restrict__ prefixes, unsigned short* __restrict__ outc)
{
    const int blk = blockIdx.x;
    const int bk = blk & 255, split = blk >> 8;      // 0..3
    const int b = bk & 15;
    const int tid = threadIdx.x;
    const int lane = tid & 63, wv = tid >> 6;
    const int quad = lane >> 4, l16 = lane & 15;
    const int cnt = counts[bk];
    const int prefix = prefixes[bk];

    __shared__ __align__(16) unsigned short albuf[32 * 584];  // 36.5 KB
    __shared__ float biasl[NOUT];

    if (tid < NOUT) biasl[tid] = biasrows[bk * NOUT + tid];

    // ---- W-build: wave wv owns cols o = wv*16 + l16; k-slices quad*8..+7.
    // bfr[ks][j] = sum_r lr[r] * basekF[ks][wv][r][lane][j]  (coalesced loads)
    const int col = wv * 16 + l16;
    float l8[NRANK];
    #pragma unroll
    for (int r = 0; r < NRANK; ++r) l8[r] = lr[bk * NRANK + r];
    const unsigned short* wb = basekF + (size_t)wv * 4096 + lane * 8;
    s16x8 bfr[18];
    #pragma unroll 2
    for (int ks = 0; ks < 18; ++ks) {
        float w[8] = {0.f, 0.f, 0.f, 0.f, 0.f, 0.f, 0.f, 0.f};
        #pragma unroll
        for (int r = 0; r < NRANK; ++r) {
            s16x8 bv = *reinterpret_cast<const s16x8*>(wb + (size_t)ks * 16384 + r * 512);
            #pragma unroll
            for (int j = 0; j < 8; ++j)
                w[j] += l8[r] * bf2f((unsigned short)bv[j]);
        }
        s16x8 f;
        #pragma unroll
        for (int j = 0; j < 8; ++j) f[j] = (short)f2bf(w[j]);
        bfr[ks] = f;
    }

    const unsigned short* xb = xcl + (size_t)b * (XH * XH * 64);
    const unsigned short* gl = lists + bk * NPIX;
    const int p = tid >> 3, part = tid & 7;      // staging role: pixel, 16B part
    const int ntile = (cnt + 31) >> 5;

    for (int t = split; t < ntile; t += 4) {
        // stage current tile (regs short-lived: load -> ds_write)
        int slot = (t << 5) + p;
        int n = (slot < cnt) ? (int)gl[slot] : 0;
        const unsigned short* xrow = xb + (((n >> 6) * XH) + (n & 63)) * 64 + part * 8;
        unsigned short* arow = albuf + p * 584 + part * 8;
        #pragma unroll
        for (int tap = 0; tap < 9; ++tap) {
            int dy = tap / 3, dx = tap - dy * 3;
            *reinterpret_cast<s16x8*>(arow + tap * 64) =
                *reinterpret_cast<const s16x8*>(xrow + (dy * XH + dx) * 64);
        }
        __syncthreads();

        f32x4 acc0 = {0.f, 0.f, 0.f, 0.f}, acc1 = {0.f, 0.f, 0.f, 0.f};
        const unsigned short* ar0 = albuf + l16 * 584 + quad * 8;
        const unsigned short* ar1 = ar0 + 16 * 584;
        #pragma unroll
        for (int ks = 0; ks < 18; ++ks) {
            s16x8 a0 = *reinterpret_cast<const s16x8*>(ar0 + ks * 32);
            s16x8 a1 = *reinterpret_cast<const s16x8*>(ar1 + ks * 32);
            acc0 = __builtin_amdgcn_mfma_f32_16x16x32_bf16(a0, bfr[ks], acc0, 0, 0, 0);
            acc1 = __builtin_amdgcn_mfma_f32_16x16x32_bf16(a1, bfr[ks], acc1, 0, 0, 0);
        }
        __syncthreads();

        // D: col = l16 (-> o), row = quad*4 + reg (-> slot)
        float bb = biasl[col];
        unsigned short* ob = outc + ((size_t)b * NPIX + prefix) * 64;
        #pragma unroll
        for (int r = 0; r < 4; ++r) {
            int s0 = (t << 5) + quad * 4 + r;
            if (s0 < cnt) ob[(size_t)s0 * 64 + col] = f2bf(acc0[r] + bb);
            int s1 = s0 + 16;
            if (s1 < cnt) ob[(size_t)s1 * 64 + col] = f2bf(acc1[r] + bb);
        }
    }
}

// ---------------------------------------------------------------------------
// k_scatter: outc bf16 [b][ptr][o] -> out f32 [b][o][n].
// Gather: 8 lanes per 128B outc row (8 segments/instr). LDS transpose with
// stride-68 u16 rows (2-way bank alias = free). Coalesced f32 stores.
// grid 256 = chunk*16 + b, 256 thr.
// ---------------------------------------------------------------------------
extern "C" __global__ __launch_bounds__(256)
void k_scatter(const int* __restrict__ labels, const unsigned short* __restrict__ slotmap,
               const int* __restrict__ prefixes, const unsigned short* __restrict__ outc,
               float* __restrict__ out)
{
    const int blk = blockIdx.x;
    const int b = blk & 15, chunk = blk >> 4;
    const int tid = threadIdx.x;
    __shared__ int pref[KC];
    __shared__ int sptr[256];
    __shared__ unsigned short tile[256 * 68];   // 34.8 KB
    if (tid < KC) pref[tid] = prefixes[tid * 16 + b];
    __syncthreads();
    const int n0 = chunk * 256;
    {
        int n = n0 + tid;
        int kk = labels[b * NPIX + n];
        sptr[tid] = pref[kk] + (int)slotmap[b * NPIX + n];
    }
    __syncthreads();
    const int pixb = tid >> 3, part = tid & 7;
    #pragma unroll
    for (int pass = 0; pass < 8; ++pass) {
        int pix = pass * 32 + pixb;
        int ptr = sptr[pix];
        s16x8 vv = *reinterpret_cast<const s16x8*>(
            outc + ((size_t)b * NPIX + ptr) * 64 + part * 8);
        s16x4 lo = {vv[0], vv[1], vv[2], vv[3]};
        s16x4 hi = {vv[4], vv[5], vv[6], vv[7]};
        *reinterpret_cast<s16x4*>(&tile[pix * 68 + part * 8]) = lo;     // 8B aligned
        *reinterpret_cast<s16x4*>(&tile[pix * 68 + part * 8 + 4]) = hi;
    }
    __syncthreads();
    float* ob = out + (size_t)b * NOUT * NPIX + n0 + tid;
    #pragma unroll
    for (int o2 = 0; o2 < 32; ++o2) {
        uint32_t pair = *reinterpret_cast<const uint32_t*>(&tile[tid * 68 + o2 * 2]);
        ob[(size_t)(2 * o2) * NPIX]     = bf2f((unsigned short)(pair & 0xffffu));
        ob[(size_t)(2 * o2 + 1) * NPIX] = bf2f((unsigned short)(pair >> 16));
    }
}

// ---------------------------------------------------------------------------
// Workspace layout — TOTAL 20,793,344 B (< 21,627,904 B proven safe):
//   lists    @ 0         : 256*4096 u16      = 2,097,152
//   counts   @ 2097152   : 256 i32           = 1,024
//   centers  @ 2098176   : 256*576 f32       = 589,824
//   biasrows @ 2688000   : 256*64 f32        = 65,536
//   lr       @ 2753536   : 256*8 f32         = 8,192
//   basekF   @ 2761728   : 72*4096 bf16      = 589,824
//   slotmap  @ 3351552   : 16*4096 u16       = 131,072
//   xcl      @ 3482624   : 16*66*66*64 bf16  = 8,921,088
//   outc     @ 12403712  : 16*4096*64 bf16   = 8,388,608
//   prefixes @ 20792320  : 256 i32           = 1,024
// ---------------------------------------------------------------------------
extern "C" void kernel_launch(void* const* d_in, const int* in_sizes, int n_in,
                              void* d_out, int out_size, void* d_ws, size_t ws_size,
                              hipStream_t stream)
{
    const float* x      = (const float*)d_in[0];
    const int*   labels = (const int*)d_in[1];
    const float* lw1    = (const float*)d_in[2];
    const float* lb1    = (const float*)d_in[3];
    const float* lw2    = (const float*)d_in[4];
    const float* lb2    = (const float*)d_in[5];
    const float* lw3    = (const float*)d_in[6];
    const float* lb3    = (const float*)d_in[7];
    const float* basek  = (const float*)d_in[8];
    const float* bw1    = (const float*)d_in[9];
    const float* bb1    = (const float*)d_in[10];
    const float* bw2    = (const float*)d_in[11];
    const float* bb2    = (const float*)d_in[12];
    float* out = (float*)d_out;

    char* ws = (char*)d_ws;
    unsigned short* lists   = (unsigned short*)(ws);
    int*            counts  = (int*)(ws + 2097152);
    float*          centers = (float*)(ws + 2098176);
    float*          biasrows= (float*)(ws + 2688000);
    float*          lr      = (float*)(ws + 2753536);
    unsigned short* basekF  = (unsigned short*)(ws + 2761728);
    unsigned short* slotmap = (unsigned short*)(ws + 3351552);
    unsigned short* xcl     = (unsigned short*)(ws + 3482624);
    unsigned short* outc    = (unsigned short*)(ws + 12403712);
    int*            prefixes= (int*)(ws + 20792320);

    k_prep<<<XH * 16, 256, 0, stream>>>(x, xcl);
    k_prepT<<<72, 256, 0, stream>>>(basek, basekF);
    k_centers<<<256, 576, 0, stream>>>(xcl, labels, lists, slotmap, counts, centers);
    k_expand<<<256, 256, 0, stream>>>(centers, counts, lw1, lb1, lw2, lb2, lw3, lb3,
                                      bw1, bb1, bw2, bb2, lr, biasrows, prefixes);
    k_main<<<1024, 256, 0, stream>>>(xcl, lists, counts, basekF, lr, biasrows,
                                     prefixes, outc);
    k_scatter<<<256, 256, 0, stream>>>(labels, slotmap, prefixes, outc, out);
}

// Round 6
// 190.789 us; speedup vs baseline: 1.0371x; 1.0371x over previous
//
#include <hip/hip_runtime.h>
#include <stdint.h>
#include <stddef.h>

// Problem constants
#define NB   16
#define NC   64
#define NH   64
#define NW   64
#define KC   16
#define NOUT 64
#define NRANK 8
#define NMLP 32
#define NF   576      // C*3*3
#define NPIX 4096     // H*W
#define XH   66       // halo height/width for channel-last copy

typedef short s16x8 __attribute__((ext_vector_type(8)));
typedef short s16x4 __attribute__((ext_vector_type(4)));
typedef float f32x4 __attribute__((ext_vector_type(4)));

__device__ __forceinline__ unsigned short f2bf(float x) {
    union { float f; uint32_t u; } v; v.f = x;
    uint32_t r = v.u + 0x7FFFu + ((v.u >> 16) & 1u);   // RTNE
    return (unsigned short)(r >> 16);
}
__device__ __forceinline__ float bf2f(unsigned short u) {
    union { uint32_t u; float f; } v; v.u = ((uint32_t)u) << 16;
    return v.f;
}

// ---------------------------------------------------------------------------
// k_prep: x [B][C][H][W] f32 -> xcl [B][66][66][64] bf16 channel-last with a
// zero halo. Coalesced via LDS transpose. grid = 66*16 (yy*16 + b), 256 thr.
// ---------------------------------------------------------------------------
extern "C" __global__ __launch_bounds__(256)
void k_prep(const float* __restrict__ x, unsigned short* __restrict__ xcl)
{
    const int blk = blockIdx.x;
    const int b = blk & 15, yy = blk >> 4;
    const int tid = threadIdx.x;
    unsigned short* dst = xcl + ((size_t)(b * XH + yy) * XH) * 64;
    if (yy == 0 || yy == XH - 1) {
        for (int e = tid; e < XH * 64; e += 256) dst[e] = 0;
        return;
    }
    __shared__ float tile[64 * 65];
    const int y = yy - 1;
    const float* src = x + (size_t)b * NC * (NH * NW) + y * NW;
    #pragma unroll
    for (int rr = 0; rr < 16; ++rr) {
        int c = rr * 4 + (tid >> 6);
        int xx = tid & 63;
        tile[c * 65 + xx] = src[(size_t)c * (NH * NW) + xx];
    }
    __syncthreads();
    for (int e = tid; e < XH * 64; e += 256) {
        int xx = e >> 6, c = e & 63;
        float v = (xx == 0 || xx == XH - 1) ? 0.f : tile[c * 65 + (xx - 1)];
        dst[e] = f2bf(v);
    }
}

// ---------------------------------------------------------------------------
// k_prepT: basek [R][F][O] (F = c*9+tap) -> basekF bf16 in the exact per-lane
// order k_main's W-build consumes:
//   basekF[(((ks*4 + wv)*8 + r)*64 + lane)*8 + j]
//     = basek[r][ c*9 + tap ][ col ]  where col = wv*16 + (lane&15),
//       f' = (lane>>4)*8 + ks*32 + j, tap = f'>>6, c = f'&63.
// => each wave W-build load is 1024B contiguous (fully coalesced).
// grid = 72 (ks*4 + wv), 256 thr; each thread writes 16 consecutive u16.
// ---------------------------------------------------------------------------
extern "C" __global__ __launch_bounds__(256)
void k_prepT(const float* __restrict__ basek, unsigned short* __restrict__ basekF)
{
    const int blk = blockIdx.x;            // ks*4 + wv
    const int ks = blk >> 2, wv = blk & 3;
    const int tid = threadIdx.x;
    unsigned short outv[16];
    #pragma unroll
    for (int i = 0; i < 16; ++i) {
        int e = tid * 16 + i;              // e = r*512 + lane*8 + j
        int r = e >> 9;
        int lane = (e >> 3) & 63;
        int j = e & 7;
        int col = wv * 16 + (lane & 15);
        int fp = (lane >> 4) * 8 + ks * 32 + j;
        int tap = fp >> 6, c = fp & 63;
        outv[i] = f2bf(basek[((size_t)r * NF + c * 9 + tap) * NOUT + col]);
    }
    unsigned short* dst = basekF + (size_t)blk * 4096 + tid * 16;
    #pragma unroll
    for (int i = 0; i < 16; ++i) dst[i] = outv[i];
}

// ---------------------------------------------------------------------------
// k_centers: per-(b,k) order-preserving pixel list + slot map + counts +
// cluster centers (coalesced gathers from L2-resident xcl: wave=tap, lane=c).
// grid 256 (k*16+b), 576 thr.
// ---------------------------------------------------------------------------
extern "C" __global__ __launch_bounds__(576)
void k_centers(const unsigned short* __restrict__ xcl, const int* __restrict__ labels,
               unsigned short* __restrict__ lists, unsigned short* __restrict__ slotmap,
               int* __restrict__ counts, float* __restrict__ centers)
{
    const int bk = blockIdx.x;
    const int b = bk & 15, k = bk >> 4;
    __shared__ unsigned short list[NPIX];   // 8 KB
    __shared__ int wcnt[9];
    const int tid = threadIdx.x;
    const int lane = tid & 63, wv = tid >> 6;
    const int* lab = labels + b * NPIX;

    int total = 0;
    for (int base = 0; base < NPIX; base += 576) {
        int n = base + tid;
        bool pred = (n < NPIX) && (lab[n] == k);
        unsigned long long m = __ballot(pred);
        if (lane == 0) wcnt[wv] = __popcll(m);
        int pre = __popcll(m & ((1ull << lane) - 1ull));
        __syncthreads();
        int wbase = total;
        for (int i = 0; i < wv; ++i) wbase += wcnt[i];
        int nt = total;
        for (int i = 0; i < 9; ++i) nt += wcnt[i];
        if (pred) {
            int slot = wbase + pre;
            list[slot] = (unsigned short)n;
            slotmap[b * NPIX + n] = (unsigned short)slot;
        }
        total = nt;
        __syncthreads();
    }
    const int cnt = total;
    unsigned short* gl = lists + bk * NPIX;
    for (int i = tid; i < cnt; i += 576) gl[i] = list[i];
    if (tid == 0) counts[bk] = cnt;

    // segmented mean gather: wave wv = tap, lane = c
    const int tap = wv;
    const int c = lane;
    const int dy = tap / 3, dx = tap - dy * 3;       // halo offsets 0..2
    const unsigned short* xb = xcl + (size_t)b * (XH * XH * 64);
    float s0 = 0.f, s1 = 0.f;
    int i = 0;
    #pragma unroll 4
    for (; i + 1 < cnt; i += 2) {
        int n0 = list[i], n1 = list[i + 1];
        s0 += bf2f(xb[((((n0 >> 6) + dy) * XH) + (n0 & 63) + dx) * 64 + c]);
        s1 += bf2f(xb[((((n1 >> 6) + dy) * XH) + (n1 & 63) + dx) * 64 + c]);
    }
    if (i < cnt) {
        int n0 = list[i];
        s0 += bf2f(xb[((((n0 >> 6) + dy) * XH) + (n0 & 63) + dx) * 64 + c]);
    }
    centers[bk * NF + c * 9 + tap] = (s0 + s1) / ((float)cnt + 1e-6f);
}

// ---------------------------------------------------------------------------
// k_expand: MLPs on centers (fp32) -> lr[bk][8], biasrows[bk][64], and
// prefixes[bk] (exclusive prefix of counts over k for each b).
// ---------------------------------------------------------------------------
extern "C" __global__ __launch_bounds__(256)
void k_expand(const float* __restrict__ centers, const int* __restrict__ counts,
              const float* __restrict__ lw1, const float* __restrict__ lb1,
              const float* __restrict__ lw2, const float* __restrict__ lb2,
              const float* __restrict__ lw3, const float* __restrict__ lb3,
              const float* __restrict__ bw1, const float* __restrict__ bb1,
              const float* __restrict__ bw2, const float* __restrict__ bb2,
              float* __restrict__ lrout, float* __restrict__ biasrows,
              int* __restrict__ prefixes)
{
    const int bk = blockIdx.x;
    const int b = bk & 15, k = bk >> 4;
    const int tid = threadIdx.x;
    __shared__ float c[NF];
    __shared__ float p1[8][NMLP], pb[8][NMLP];
    __shared__ float h1[NMLP], h2[NMLP], hb[NMLP];

    for (int i = tid; i < NF; i += 256) c[i] = centers[bk * NF + i];
    if (tid == 224) {
        int s = 0;
        for (int kk = 0; kk < k; ++kk) s += counts[kk * 16 + b];
        prefixes[bk] = s;
    }
    __syncthreads();

    {   // layer-1 of both MLPs
        const int j = tid & 31, ch = tid >> 5;       // 8 chunks x 72 feats
        float a1 = 0.f, a2 = 0.f;
        for (int i = 0; i < 72; ++i) {
            int f = ch * 72 + i;
            float cv = c[f];
            a1 += cv * lw1[f * NMLP + j];
            a2 += cv * bw1[f * NMLP + j];
        }
        p1[ch][j] = a1; pb[ch][j] = a2;
    }
    __syncthreads();
    if (tid < NMLP) {
        float a = lb1[tid];
        for (int i = 0; i < 8; ++i) a += p1[i][tid];
        h1[tid] = fmaxf(a, 0.f);
    } else if (tid < 2 * NMLP) {
        int j = tid - NMLP;
        float a = bb1[j];
        for (int i = 0; i < 8; ++i) a += pb[i][j];
        hb[j] = fmaxf(a, 0.f);
    }
    __syncthreads();
    if (tid < NMLP) {
        float a = lb2[tid];
        for (int i = 0; i < NMLP; ++i) a += h1[i] * lw2[i * NMLP + tid];
        h2[tid] = fmaxf(a, 0.f);
    } else if (tid >= 64 && tid < 128) {
        int o = tid - 64;
        float a = bb2[o];
        for (int i = 0; i < NMLP; ++i) a += hb[i] * bw2[i * NOUT + o];
        biasrows[bk * NOUT + o] = a;
    }
    __syncthreads();
    if (tid < NRANK) {
        float a = lb3[tid];
        for (int i = 0; i < NMLP; ++i) a += h2[i] * lw3[i * NRANK + tid];
        lrout[bk * NRANK + tid] = a;
    }
}

// ---------------------------------------------------------------------------
// k_main: gathered GEMM. grid 1024 = 4 splits x 256 (b,k); 256 thr.
// No launch_bounds min-waves cap (R5 lesson: cap 128 forced bfr[18] spill,
// 288 B/thread scratch traffic). W-build peak pressure bounded by hand:
// ks-loop unroll 1, r in two groups of 4 loads (live ~106 VGPR).
// Output compact bf16 outc[b][prefix+slot][o].
// ---------------------------------------------------------------------------
extern "C" __global__ __launch_bounds__(256)
void k_main(const unsigned short* __restrict__ xcl, const unsigned short* __restrict__ lists,
            const int* __restrict__ counts, const unsigned short* __restrict__ basekF,
            const float* __restrict__ lr, const float* __restrict__ biasrows,
            const int* __restrict__ prefixes, unsigned short* __restrict__ outc)
{
    const int blk = blockIdx.x;
    const int bk = blk & 255, split = blk >> 8;      // 0..3
    const int b = bk & 15;
    const int tid = threadIdx.x;
    const int lane = tid & 63, wv = tid >> 6;
    const int quad = lane >> 4, l16 = lane & 15;
    const int cnt = counts[bk];
    const int prefix = prefixes[bk];

    __shared__ __align__(16) unsigned short albuf[32 * 584];  // 36.5 KB
    __shared__ float biasl[NOUT];

    if (tid < NOUT) biasl[tid] = biasrows[bk * NOUT + tid];

    // ---- W-build: wave wv owns cols o = wv*16 + l16; k-slices quad*8..+7.
    // bfr[ks][j] = sum_r lr[r] * basekF[ks][wv][r][lane][j]  (coalesced loads)
    const int col = wv * 16 + l16;
    float l8[NRANK];
    #pragma unroll
    for (int r = 0; r < NRANK; ++r) l8[r] = lr[bk * NRANK + r];
    const unsigned short* wb = basekF + (size_t)wv * 4096 + lane * 8;
    s16x8 bfr[18];
    #pragma unroll 1
    for (int ks = 0; ks < 18; ++ks) {
        const unsigned short* wk = wb + (size_t)ks * 16384;
        float w[8] = {0.f, 0.f, 0.f, 0.f, 0.f, 0.f, 0.f, 0.f};
        #pragma unroll 1
        for (int rr = 0; rr < 2; ++rr) {
            s16x8 b0 = *reinterpret_cast<const s16x8*>(wk + (rr * 4 + 0) * 512);
            s16x8 b1 = *reinterpret_cast<const s16x8*>(wk + (rr * 4 + 1) * 512);
            s16x8 b2 = *reinterpret_cast<const s16x8*>(wk + (rr * 4 + 2) * 512);
            s16x8 b3 = *reinterpret_cast<const s16x8*>(wk + (rr * 4 + 3) * 512);
            float l0 = l8[rr * 4 + 0], l1 = l8[rr * 4 + 1];
            float l2 = l8[rr * 4 + 2], l3 = l8[rr * 4 + 3];
            #pragma unroll
            for (int j = 0; j < 8; ++j) {
                w[j] += l0 * bf2f((unsigned short)b0[j]);
                w[j] += l1 * bf2f((unsigned short)b1[j]);
                w[j] += l2 * bf2f((unsigned short)b2[j]);
                w[j] += l3 * bf2f((unsigned short)b3[j]);
            }
        }
        s16x8 f;
        #pragma unroll
        for (int j = 0; j < 8; ++j) f[j] = (short)f2bf(w[j]);
        bfr[ks] = f;
    }

    const unsigned short* xb = xcl + (size_t)b * (XH * XH * 64);
    const unsigned short* gl = lists + bk * NPIX;
    const int p = tid >> 3, part = tid & 7;      // staging role: pixel, 16B part
    const int ntile = (cnt + 31) >> 5;

    for (int t = split; t < ntile; t += 4) {
        // stage current tile (regs short-lived: load -> ds_write)
        int slot = (t << 5) + p;
        int n = (slot < cnt) ? (int)gl[slot] : 0;
        const unsigned short* xrow = xb + (((n >> 6) * XH) + (n & 63)) * 64 + part * 8;
        unsigned short* arow = albuf + p * 584 + part * 8;
        #pragma unroll
        for (int tap = 0; tap < 9; ++tap) {
            int dy = tap / 3, dx = tap - dy * 3;
            *reinterpret_cast<s16x8*>(arow + tap * 64) =
                *reinterpret_cast<const s16x8*>(xrow + (dy * XH + dx) * 64);
        }
        __syncthreads();

        f32x4 acc0 = {0.f, 0.f, 0.f, 0.f}, acc1 = {0.f, 0.f, 0.f, 0.f};
        const unsigned short* ar0 = albuf + l16 * 584 + quad * 8;
        const unsigned short* ar1 = ar0 + 16 * 584;
        #pragma unroll
        for (int ks = 0; ks < 18; ++ks) {
            s16x8 a0 = *reinterpret_cast<const s16x8*>(ar0 + ks * 32);
            s16x8 a1 = *reinterpret_cast<const s16x8*>(ar1 + ks * 32);
            acc0 = __builtin_amdgcn_mfma_f32_16x16x32_bf16(a0, bfr[ks], acc0, 0, 0, 0);
            acc1 = __builtin_amdgcn_mfma_f32_16x16x32_bf16(a1, bfr[ks], acc1, 0, 0, 0);
        }
        __syncthreads();

        // D: col = l16 (-> o), row = quad*4 + reg (-> slot)
        float bb = biasl[col];
        unsigned short* ob = outc + ((size_t)b * NPIX + prefix) * 64;
        #pragma unroll
        for (int r = 0; r < 4; ++r) {
            int s0 = (t << 5) + quad * 4 + r;
            if (s0 < cnt) ob[(size_t)s0 * 64 + col] = f2bf(acc0[r] + bb);
            int s1 = s0 + 16;
            if (s1 < cnt) ob[(size_t)s1 * 64 + col] = f2bf(acc1[r] + bb);
        }
    }
}

// ---------------------------------------------------------------------------
// k_scatter: outc bf16 [b][ptr][o] -> out f32 [b][o][n].
// Gather: 8 lanes per 128B outc row (8 segments/instr). LDS transpose with
// stride-68 u16 rows (2-way bank alias = free). Coalesced f32 stores.
// grid 256 = chunk*16 + b, 256 thr.
// ---------------------------------------------------------------------------
extern "C" __global__ __launch_bounds__(256)
void k_scatter(const int* __restrict__ labels, const unsigned short* __restrict__ slotmap,
               const int* __restrict__ prefixes, const unsigned short* __restrict__ outc,
               float* __restrict__ out)
{
    const int blk = blockIdx.x;
    const int b = blk & 15, chunk = blk >> 4;
    const int tid = threadIdx.x;
    __shared__ int pref[KC];
    __shared__ int sptr[256];
    __shared__ unsigned short tile[256 * 68];   // 34.8 KB
    if (tid < KC) pref[tid] = prefixes[tid * 16 + b];
    __syncthreads();
    const int n0 = chunk * 256;
    {
        int n = n0 + tid;
        int kk = labels[b * NPIX + n];
        sptr[tid] = pref[kk] + (int)slotmap[b * NPIX + n];
    }
    __syncthreads();
    const int pixb = tid >> 3, part = tid & 7;
    #pragma unroll
    for (int pass = 0; pass < 8; ++pass) {
        int pix = pass * 32 + pixb;
        int ptr = sptr[pix];
        s16x8 vv = *reinterpret_cast<const s16x8*>(
            outc + ((size_t)b * NPIX + ptr) * 64 + part * 8);
        s16x4 lo = {vv[0], vv[1], vv[2], vv[3]};
        s16x4 hi = {vv[4], vv[5], vv[6], vv[7]};
        *reinterpret_cast<s16x4*>(&tile[pix * 68 + part * 8]) = lo;     // 8B aligned
        *reinterpret_cast<s16x4*>(&tile[pix * 68 + part * 8 + 4]) = hi;
    }
    __syncthreads();
    float* ob = out + (size_t)b * NOUT * NPIX + n0 + tid;
    #pragma unroll
    for (int o2 = 0; o2 < 32; ++o2) {
        uint32_t pair = *reinterpret_cast<const uint32_t*>(&tile[tid * 68 + o2 * 2]);
        ob[(size_t)(2 * o2) * NPIX]     = bf2f((unsigned short)(pair & 0xffffu));
        ob[(size_t)(2 * o2 + 1) * NPIX] = bf2f((unsigned short)(pair >> 16));
    }
}

// ---------------------------------------------------------------------------
// Workspace layout — TOTAL 20,793,344 B (< 21,627,904 B proven safe):
//   lists    @ 0         : 256*4096 u16      = 2,097,152
//   counts   @ 2097152   : 256 i32           = 1,024
//   centers  @ 2098176   : 256*576 f32       = 589,824
//   biasrows @ 2688000   : 256*64 f32        = 65,536
//   lr       @ 2753536   : 256*8 f32         = 8,192
//   basekF   @ 2761728   : 72*4096 bf16      = 589,824
//   slotmap  @ 3351552   : 16*4096 u16       = 131,072
//   xcl      @ 3482624   : 16*66*66*64 bf16  = 8,921,088
//   outc     @ 12403712  : 16*4096*64 bf16   = 8,388,608
//   prefixes @ 20792320  : 256 i32           = 1,024
// ---------------------------------------------------------------------------
extern "C" void kernel_launch(void* const* d_in, const int* in_sizes, int n_in,
                              void* d_out, int out_size, void* d_ws, size_t ws_size,
                              hipStream_t stream)
{
    const float* x      = (const float*)d_in[0];
    const int*   labels = (const int*)d_in[1];
    const float* lw1    = (const float*)d_in[2];
    const float* lb1    = (const float*)d_in[3];
    const float* lw2    = (const float*)d_in[4];
    const float* lb2    = (const float*)d_in[5];
    const float* lw3    = (const float*)d_in[6];
    const float* lb3    = (const float*)d_in[7];
    const float* basek  = (const float*)d_in[8];
    const float* bw1    = (const float*)d_in[9];
    const float* bb1    = (const float*)d_in[10];
    const float* bw2    = (const float*)d_in[11];
    const float* bb2    = (const float*)d_in[12];
    float* out = (float*)d_out;

    char* ws = (char*)d_ws;
    unsigned short* lists   = (unsigned short*)(ws);
    int*            counts  = (int*)(ws + 2097152);
    float*          centers = (float*)(ws + 2098176);
    float*          biasrows= (float*)(ws + 2688000);
    float*          lr      = (float*)(ws + 2753536);
    unsigned short* basekF  = (unsigned short*)(ws + 2761728);
    unsigned short* slotmap = (unsigned short*)(ws + 3351552);
    unsigned short* xcl     = (unsigned short*)(ws + 3482624);
    unsigned short* outc    = (unsigned short*)(ws + 12403712);
    int*            prefixes= (int*)(ws + 20792320);

    k_prep<<<XH * 16, 256, 0, stream>>>(x, xcl);
    k_prepT<<<72, 256, 0, stream>>>(basek, basekF);
    k_centers<<<256, 576, 0, stream>>>(xcl, labels, lists, slotmap, counts, centers);
    k_expand<<<256, 256, 0, stream>>>(centers, counts, lw1, lb1, lw2, lb2, lw3, lb3,
                                      bw1, bb1, bw2, bb2, lr, biasrows, prefixes);
    k_main<<<1024, 256, 0, stream>>>(xcl, lists, counts, basekF, lr, biasrows,
                                     prefixes, outc);
    k_scatter<<<256, 256, 0, stream>>>(labels, slotmap, prefixes, outc, out);
}

// Round 7
// 169.537 us; speedup vs baseline: 1.1671x; 1.1254x over previous
//
#include <hip/hip_runtime.h>
#include <stdint.h>
#include <stddef.h>

// Problem constants
#define NB   16
#define NC   64
#define NH   64
#define NW   64
#define KC   16
#define NOUT 64
#define NRANK 8
#define NMLP 32
#define NF   576      // C*3*3
#define NPIX 4096     // H*W
#define XH   66       // halo height/width for channel-last copy

typedef short s16x8 __attribute__((ext_vector_type(8)));
typedef short s16x4 __attribute__((ext_vector_type(4)));
typedef float f32x4 __attribute__((ext_vector_type(4)));

__device__ __forceinline__ unsigned short f2bf(float x) {
    union { float f; uint32_t u; } v; v.f = x;
    uint32_t r = v.u + 0x7FFFu + ((v.u >> 16) & 1u);   // RTNE
    return (unsigned short)(r >> 16);
}
__device__ __forceinline__ float bf2f(unsigned short u) {
    union { uint32_t u; float f; } v; v.u = ((uint32_t)u) << 16;
    return v.f;
}

// ---------------------------------------------------------------------------
// k_prep: x [B][C][H][W] f32 -> xcl [B][66][66][64] bf16 channel-last with a
// zero halo. Coalesced via LDS transpose. grid = 66*16 (yy*16 + b), 256 thr.
// ---------------------------------------------------------------------------
extern "C" __global__ __launch_bounds__(256)
void k_prep(const float* __restrict__ x, unsigned short* __restrict__ xcl)
{
    const int blk = blockIdx.x;
    const int b = blk & 15, yy = blk >> 4;
    const int tid = threadIdx.x;
    unsigned short* dst = xcl + ((size_t)(b * XH + yy) * XH) * 64;
    if (yy == 0 || yy == XH - 1) {
        for (int e = tid; e < XH * 64; e += 256) dst[e] = 0;
        return;
    }
    __shared__ float tile[64 * 65];
    const int y = yy - 1;
    const float* src = x + (size_t)b * NC * (NH * NW) + y * NW;
    #pragma unroll
    for (int rr = 0; rr < 16; ++rr) {
        int c = rr * 4 + (tid >> 6);
        int xx = tid & 63;
        tile[c * 65 + xx] = src[(size_t)c * (NH * NW) + xx];
    }
    __syncthreads();
    for (int e = tid; e < XH * 64; e += 256) {
        int xx = e >> 6, c = e & 63;
        float v = (xx == 0 || xx == XH - 1) ? 0.f : tile[c * 65 + (xx - 1)];
        dst[e] = f2bf(v);
    }
}

// ---------------------------------------------------------------------------
// k_prepT: basek [R][F][O] (F = c*9+tap) -> basekF bf16 in the exact per-lane
// order k_main's W-build consumes:
//   basekF[(((ks*4 + wv)*8 + r)*64 + lane)*8 + j]
//     = basek[r][ c*9 + tap ][ col ]  where col = wv*16 + (lane&15),
//       f' = (lane>>4)*8 + ks*32 + j, tap = f'>>6, c = f'&63.
// => each wave W-build load is 1024B contiguous (fully coalesced).
// grid = 72 (ks*4 + wv), 256 thr; each thread writes 16 consecutive u16.
// ---------------------------------------------------------------------------
extern "C" __global__ __launch_bounds__(256)
void k_prepT(const float* __restrict__ basek, unsigned short* __restrict__ basekF)
{
    const int blk = blockIdx.x;            // ks*4 + wv
    const int ks = blk >> 2, wv = blk & 3;
    const int tid = threadIdx.x;
    unsigned short outv[16];
    #pragma unroll
    for (int i = 0; i < 16; ++i) {
        int e = tid * 16 + i;              // e = r*512 + lane*8 + j
        int r = e >> 9;
        int lane = (e >> 3) & 63;
        int j = e & 7;
        int col = wv * 16 + (lane & 15);
        int fp = (lane >> 4) * 8 + ks * 32 + j;
        int tap = fp >> 6, c = fp & 63;
        outv[i] = f2bf(basek[((size_t)r * NF + c * 9 + tap) * NOUT + col]);
    }
    unsigned short* dst = basekF + (size_t)blk * 4096 + tid * 16;
    #pragma unroll
    for (int i = 0; i < 16; ++i) dst[i] = outv[i];
}

// ---------------------------------------------------------------------------
// k_centers: per-(b,k) order-preserving pixel list + slot map + counts +
// cluster centers (coalesced gathers from L2-resident xcl: wave=tap, lane=c).
// grid 256 (k*16+b), 576 thr.
// ---------------------------------------------------------------------------
extern "C" __global__ __launch_bounds__(576)
void k_centers(const unsigned short* __restrict__ xcl, const int* __restrict__ labels,
               unsigned short* __restrict__ lists, unsigned short* __restrict__ slotmap,
               int* __restrict__ counts, float* __restrict__ centers)
{
    const int bk = blockIdx.x;
    const int b = bk & 15, k = bk >> 4;
    __shared__ unsigned short list[NPIX];   // 8 KB
    __shared__ int wcnt[9];
    const int tid = threadIdx.x;
    const int lane = tid & 63, wv = tid >> 6;
    const int* lab = labels + b * NPIX;

    int total = 0;
    for (int base = 0; base < NPIX; base += 576) {
        int n = base + tid;
        bool pred = (n < NPIX) && (lab[n] == k);
        unsigned long long m = __ballot(pred);
        if (lane == 0) wcnt[wv] = __popcll(m);
        int pre = __popcll(m & ((1ull << lane) - 1ull));
        __syncthreads();
        int wbase = total;
        for (int i = 0; i < wv; ++i) wbase += wcnt[i];
        int nt = total;
        for (int i = 0; i < 9; ++i) nt += wcnt[i];
        if (pred) {
            int slot = wbase + pre;
            list[slot] = (unsigned short)n;
            slotmap[b * NPIX + n] = (unsigned short)slot;
        }
        total = nt;
        __syncthreads();
    }
    const int cnt = total;
    unsigned short* gl = lists + bk * NPIX;
    for (int i = tid; i < cnt; i += 576) gl[i] = list[i];
    if (tid == 0) counts[bk] = cnt;

    // segmented mean gather: wave wv = tap, lane = c
    const int tap = wv;
    const int c = lane;
    const int dy = tap / 3, dx = tap - dy * 3;       // halo offsets 0..2
    const unsigned short* xb = xcl + (size_t)b * (XH * XH * 64);
    float s0 = 0.f, s1 = 0.f;
    int i = 0;
    #pragma unroll 4
    for (; i + 1 < cnt; i += 2) {
        int n0 = list[i], n1 = list[i + 1];
        s0 += bf2f(xb[((((n0 >> 6) + dy) * XH) + (n0 & 63) + dx) * 64 + c]);
        s1 += bf2f(xb[((((n1 >> 6) + dy) * XH) + (n1 & 63) + dx) * 64 + c]);
    }
    if (i < cnt) {
        int n0 = list[i];
        s0 += bf2f(xb[((((n0 >> 6) + dy) * XH) + (n0 & 63) + dx) * 64 + c]);
    }
    centers[bk * NF + c * 9 + tap] = (s0 + s1) / ((float)cnt + 1e-6f);
}

// ---------------------------------------------------------------------------
// k_expand: MLPs on centers (fp32) -> lr[bk][8], biasrows[bk][64], and
// prefixes[bk] (exclusive prefix of counts over k for each b).
// ---------------------------------------------------------------------------
extern "C" __global__ __launch_bounds__(256)
void k_expand(const float* __restrict__ centers, const int* __restrict__ counts,
              const float* __restrict__ lw1, const float* __restrict__ lb1,
              const float* __restrict__ lw2, const float* __restrict__ lb2,
              const float* __restrict__ lw3, const float* __restrict__ lb3,
              const float* __restrict__ bw1, const float* __restrict__ bb1,
              const float* __restrict__ bw2, const float* __restrict__ bb2,
              float* __restrict__ lrout, float* __restrict__ biasrows,
              int* __restrict__ prefixes)
{
    const int bk = blockIdx.x;
    const int b = bk & 15, k = bk >> 4;
    const int tid = threadIdx.x;
    __shared__ float c[NF];
    __shared__ float p1[8][NMLP], pb[8][NMLP];
    __shared__ float h1[NMLP], h2[NMLP], hb[NMLP];

    for (int i = tid; i < NF; i += 256) c[i] = centers[bk * NF + i];
    if (tid == 224) {
        int s = 0;
        for (int kk = 0; kk < k; ++kk) s += counts[kk * 16 + b];
        prefixes[bk] = s;
    }
    __syncthreads();

    {   // layer-1 of both MLPs
        const int j = tid & 31, ch = tid >> 5;       // 8 chunks x 72 feats
        float a1 = 0.f, a2 = 0.f;
        for (int i = 0; i < 72; ++i) {
            int f = ch * 72 + i;
            float cv = c[f];
            a1 += cv * lw1[f * NMLP + j];
            a2 += cv * bw1[f * NMLP + j];
        }
        p1[ch][j] = a1; pb[ch][j] = a2;
    }
    __syncthreads();
    if (tid < NMLP) {
        float a = lb1[tid];
        for (int i = 0; i < 8; ++i) a += p1[i][tid];
        h1[tid] = fmaxf(a, 0.f);
    } else if (tid < 2 * NMLP) {
        int j = tid - NMLP;
        float a = bb1[j];
        for (int i = 0; i < 8; ++i) a += pb[i][j];
        hb[j] = fmaxf(a, 0.f);
    }
    __syncthreads();
    if (tid < NMLP) {
        float a = lb2[tid];
        for (int i = 0; i < NMLP; ++i) a += h1[i] * lw2[i * NMLP + tid];
        h2[tid] = fmaxf(a, 0.f);
    } else if (tid >= 64 && tid < 128) {
        int o = tid - 64;
        float a = bb2[o];
        for (int i = 0; i < NMLP; ++i) a += hb[i] * bw2[i * NOUT + o];
        biasrows[bk * NOUT + o] = a;
    }
    __syncthreads();
    if (tid < NRANK) {
        float a = lb3[tid];
        for (int i = 0; i < NMLP; ++i) a += h2[i] * lw3[i * NRANK + tid];
        lrout[bk * NRANK + tid] = a;
    }
}

// ---------------------------------------------------------------------------
// k_main: gathered GEMM. grid 1024 = 4 splits x 256 (b,k); 256 thr.
// W-build ks-loop FULLY unrolled: partially-unrolled loops made bfr[ks] a
// dynamically-indexed local array -> forced scratch allocation (the R4-R6
// 320 B/thread spill). Full unroll = constant indices = registers (R3 proof:
// VGPR 124, FETCH 6.9 MB). Coalesced basekF layout kept.
// Output compact bf16 outc[b][prefix+slot][o].
// ---------------------------------------------------------------------------
extern "C" __global__ __launch_bounds__(256)
void k_main(const unsigned short* __restrict__ xcl, const unsigned short* __restrict__ lists,
            const int* __restrict__ counts, const unsigned short* __restrict__ basekF,
            const float* __restrict__ lr, const float* __restrict__ biasrows,
            const int* __restrict__ prefixes, unsigned short* __restrict__ outc)
{
    const int blk = blockIdx.x;
    const int bk = blk & 255, split = blk >> 8;      // 0..3
    const int b = bk & 15;
    const int tid = threadIdx.x;
    const int lane = tid & 63, wv = tid >> 6;
    const int quad = lane >> 4, l16 = lane & 15;
    const int cnt = counts[bk];
    const int prefix = prefixes[bk];

    __shared__ __align__(16) unsigned short albuf[32 * 584];  // 36.5 KB
    __shared__ float biasl[NOUT];

    if (tid < NOUT) biasl[tid] = biasrows[bk * NOUT + tid];

    // ---- W-build: wave wv owns cols o = wv*16 + l16; k-slices quad*8..+7.
    // bfr[ks][j] = sum_r lr[r] * basekF[ks][wv][r][lane][j]  (coalesced loads)
    const int col = wv * 16 + l16;
    float l8[NRANK];
    #pragma unroll
    for (int r = 0; r < NRANK; ++r) l8[r] = lr[bk * NRANK + r];
    const unsigned short* wb = basekF + (size_t)wv * 4096 + lane * 8;
    s16x8 bfr[18];
    #pragma unroll
    for (int ks = 0; ks < 18; ++ks) {
        const unsigned short* wk = wb + (size_t)ks * 16384;
        float w[8] = {0.f, 0.f, 0.f, 0.f, 0.f, 0.f, 0.f, 0.f};
        #pragma unroll
        for (int r = 0; r < NRANK; ++r) {
            s16x8 bv = *reinterpret_cast<const s16x8*>(wk + r * 512);
            #pragma unroll
            for (int j = 0; j < 8; ++j)
                w[j] += l8[r] * bf2f((unsigned short)bv[j]);
        }
        s16x8 f;
        #pragma unroll
        for (int j = 0; j < 8; ++j) f[j] = (short)f2bf(w[j]);
        bfr[ks] = f;
    }

    const unsigned short* xb = xcl + (size_t)b * (XH * XH * 64);
    const unsigned short* gl = lists + bk * NPIX;
    const int p = tid >> 3, part = tid & 7;      // staging role: pixel, 16B part
    const int ntile = (cnt + 31) >> 5;

    for (int t = split; t < ntile; t += 4) {
        // stage current tile (regs short-lived: load -> ds_write)
        int slot = (t << 5) + p;
        int n = (slot < cnt) ? (int)gl[slot] : 0;
        const unsigned short* xrow = xb + (((n >> 6) * XH) + (n & 63)) * 64 + part * 8;
        unsigned short* arow = albuf + p * 584 + part * 8;
        #pragma unroll
        for (int tap = 0; tap < 9; ++tap) {
            int dy = tap / 3, dx = tap - dy * 3;
            *reinterpret_cast<s16x8*>(arow + tap * 64) =
                *reinterpret_cast<const s16x8*>(xrow + (dy * XH + dx) * 64);
        }
        __syncthreads();

        f32x4 acc0 = {0.f, 0.f, 0.f, 0.f}, acc1 = {0.f, 0.f, 0.f, 0.f};
        const unsigned short* ar0 = albuf + l16 * 584 + quad * 8;
        const unsigned short* ar1 = ar0 + 16 * 584;
        #pragma unroll
        for (int ks = 0; ks < 18; ++ks) {
            s16x8 a0 = *reinterpret_cast<const s16x8*>(ar0 + ks * 32);
            s16x8 a1 = *reinterpret_cast<const s16x8*>(ar1 + ks * 32);
            acc0 = __builtin_amdgcn_mfma_f32_16x16x32_bf16(a0, bfr[ks], acc0, 0, 0, 0);
            acc1 = __builtin_amdgcn_mfma_f32_16x16x32_bf16(a1, bfr[ks], acc1, 0, 0, 0);
        }
        __syncthreads();

        // D: col = l16 (-> o), row = quad*4 + reg (-> slot)
        float bb = biasl[col];
        unsigned short* ob = outc + ((size_t)b * NPIX + prefix) * 64;
        #pragma unroll
        for (int r = 0; r < 4; ++r) {
            int s0 = (t << 5) + quad * 4 + r;
            if (s0 < cnt) ob[(size_t)s0 * 64 + col] = f2bf(acc0[r] + bb);
            int s1 = s0 + 16;
            if (s1 < cnt) ob[(size_t)s1 * 64 + col] = f2bf(acc1[r] + bb);
        }
    }
}

// ---------------------------------------------------------------------------
// k_scatter: outc bf16 [b][ptr][o] -> out f32 [b][o][n].
// Gather: 8 lanes per 128B outc row (8 segments/instr). LDS transpose with
// stride-68 u16 rows (2-way bank alias = free). Coalesced f32 stores.
// grid 256 = chunk*16 + b, 256 thr.
// ---------------------------------------------------------------------------
extern "C" __global__ __launch_bounds__(256)
void k_scatter(const int* __restrict__ labels, const unsigned short* __restrict__ slotmap,
               const int* __restrict__ prefixes, const unsigned short* __restrict__ outc,
               float* __restrict__ out)
{
    const int blk = blockIdx.x;
    const int b = blk & 15, chunk = blk >> 4;
    const int tid = threadIdx.x;
    __shared__ int pref[KC];
    __shared__ int sptr[256];
    __shared__ unsigned short tile[256 * 68];   // 34.8 KB
    if (tid < KC) pref[tid] = prefixes[tid * 16 + b];
    __syncthreads();
    const int n0 = chunk * 256;
    {
        int n = n0 + tid;
        int kk = labels[b * NPIX + n];
        sptr[tid] = pref[kk] + (int)slotmap[b * NPIX + n];
    }
    __syncthreads();
    const int pixb = tid >> 3, part = tid & 7;
    #pragma unroll
    for (int pass = 0; pass < 8; ++pass) {
        int pix = pass * 32 + pixb;
        int ptr = sptr[pix];
        s16x8 vv = *reinterpret_cast<const s16x8*>(
            outc + ((size_t)b * NPIX + ptr) * 64 + part * 8);
        s16x4 lo = {vv[0], vv[1], vv[2], vv[3]};
        s16x4 hi = {vv[4], vv[5], vv[6], vv[7]};
        *reinterpret_cast<s16x4*>(&tile[pix * 68 + part * 8]) = lo;     // 8B aligned
        *reinterpret_cast<s16x4*>(&tile[pix * 68 + part * 8 + 4]) = hi;
    }
    __syncthreads();
    float* ob = out + (size_t)b * NOUT * NPIX + n0 + tid;
    #pragma unroll
    for (int o2 = 0; o2 < 32; ++o2) {
        uint32_t pair = *reinterpret_cast<const uint32_t*>(&tile[tid * 68 + o2 * 2]);
        ob[(size_t)(2 * o2) * NPIX]     = bf2f((unsigned short)(pair & 0xffffu));
        ob[(size_t)(2 * o2 + 1) * NPIX] = bf2f((unsigned short)(pair >> 16));
    }
}

// ---------------------------------------------------------------------------
// Workspace layout — TOTAL 20,793,344 B (< 21,627,904 B proven safe):
//   lists    @ 0         : 256*4096 u16      = 2,097,152
//   counts   @ 2097152   : 256 i32           = 1,024
//   centers  @ 2098176   : 256*576 f32       = 589,824
//   biasrows @ 2688000   : 256*64 f32        = 65,536
//   lr       @ 2753536   : 256*8 f32         = 8,192
//   basekF   @ 2761728   : 72*4096 bf16      = 589,824
//   slotmap  @ 3351552   : 16*4096 u16       = 131,072
//   xcl      @ 3482624   : 16*66*66*64 bf16  = 8,921,088
//   outc     @ 12403712  : 16*4096*64 bf16   = 8,388,608
//   prefixes @ 20792320  : 256 i32           = 1,024
// ---------------------------------------------------------------------------
extern "C" void kernel_launch(void* const* d_in, const int* in_sizes, int n_in,
                              void* d_out, int out_size, void* d_ws, size_t ws_size,
                              hipStream_t stream)
{
    const float* x      = (const float*)d_in[0];
    const int*   labels = (const int*)d_in[1];
    const float* lw1    = (const float*)d_in[2];
    const float* lb1    = (const float*)d_in[3];
    const float* lw2    = (const float*)d_in[4];
    const float* lb2    = (const float*)d_in[5];
    const float* lw3    = (const float*)d_in[6];
    const float* lb3    = (const float*)d_in[7];
    const float* basek  = (const float*)d_in[8];
    const float* bw1    = (const float*)d_in[9];
    const float* bb1    = (const float*)d_in[10];
    const float* bw2    = (const float*)d_in[11];
    const float* bb2    = (const float*)d_in[12];
    float* out = (float*)d_out;

    char* ws = (char*)d_ws;
    unsigned short* lists   = (unsigned short*)(ws);
    int*            counts  = (int*)(ws + 2097152);
    float*          centers = (float*)(ws + 2098176);
    float*          biasrows= (float*)(ws + 2688000);
    float*          lr      = (float*)(ws + 2753536);
    unsigned short* basekF  = (unsigned short*)(ws + 2761728);
    unsigned short* slotmap = (unsigned short*)(ws + 3351552);
    unsigned short* xcl     = (unsigned short*)(ws + 3482624);
    unsigned short* outc    = (unsigned short*)(ws + 12403712);
    int*            prefixes= (int*)(ws + 20792320);

    k_prep<<<XH * 16, 256, 0, stream>>>(x, xcl);
    k_prepT<<<72, 256, 0, stream>>>(basek, basekF);
    k_centers<<<256, 576, 0, stream>>>(xcl, labels, lists, slotmap, counts, centers);
    k_expand<<<256, 256, 0, stream>>>(centers, counts, lw1, lb1, lw2, lb2, lw3, lb3,
                                      bw1, bb1, bw2, bb2, lr, biasrows, prefixes);
    k_main<<<1024, 256, 0, stream>>>(xcl, lists, counts, basekF, lr, biasrows,
                                     prefixes, outc);
    k_scatter<<<256, 256, 0, stream>>>(labels, slotmap, prefixes, outc, out);
}

// Round 8
// 155.834 us; speedup vs baseline: 1.2697x; 1.0879x over previous
//
#include <hip/hip_runtime.h>
#include <stdint.h>
#include <stddef.h>

// Problem constants
#define NB   16
#define NC   64
#define NH   64
#define NW   64
#define KC   16
#define NOUT 64
#define NRANK 8
#define NMLP 32
#define NF   576      // C*3*3
#define NPIX 4096     // H*W
#define XH   66       // halo height/width for channel-last copy

typedef short s16x8 __attribute__((ext_vector_type(8)));
typedef short s16x4 __attribute__((ext_vector_type(4)));
typedef float f32x4 __attribute__((ext_vector_type(4)));

__device__ __forceinline__ unsigned short f2bf(float x) {
    union { float f; uint32_t u; } v; v.f = x;
    uint32_t r = v.u + 0x7FFFu + ((v.u >> 16) & 1u);   // RTNE
    return (unsigned short)(r >> 16);
}
__device__ __forceinline__ float bf2f(unsigned short u) {
    union { uint32_t u; float f; } v; v.u = ((uint32_t)u) << 16;
    return v.f;
}

// ---------------------------------------------------------------------------
// k_prep_all: fused input prep.
//  blocks [0, 1056): x [B][C][H][W] f32 -> xcl [B][66][66][64] bf16
//    channel-last with zero halo; LDS transpose; s16x8 (16B) stores.
//  blocks [1056, 1128): basek [R][F][O] -> basekF bf16 in k_main's exact
//    per-lane W-build order (1024B contiguous per wave load).
// ---------------------------------------------------------------------------
extern "C" __global__ __launch_bounds__(256)
void k_prep_all(const float* __restrict__ x, const float* __restrict__ basek,
                unsigned short* __restrict__ xcl, unsigned short* __restrict__ basekF)
{
    __shared__ float tile[64 * 65];
    const int blk0 = blockIdx.x;
    const int tid = threadIdx.x;
    if (blk0 < XH * 16) {
        const int b = blk0 & 15, yy = blk0 >> 4;
        unsigned short* dst = xcl + ((size_t)(b * XH + yy) * XH) * 64;
        if (yy == 0 || yy == XH - 1) {
            for (int e = tid; e < XH * 64; e += 256) dst[e] = 0;
            return;
        }
        const int y = yy - 1;
        const float* src = x + (size_t)b * NC * (NH * NW) + y * NW;
        #pragma unroll
        for (int rr = 0; rr < 16; ++rr) {
            int c = rr * 4 + (tid >> 6);
            int xx = tid & 63;
            tile[c * 65 + xx] = src[(size_t)c * (NH * NW) + xx];
        }
        __syncthreads();
        // 66*64 u16 = 528 chunks of 8; each chunk one row xx, channels c0..c0+7
        for (int ee = tid; ee < 528; ee += 256) {
            int xx = ee >> 3;
            int c0 = (ee & 7) * 8;
            s16x8 v;
            #pragma unroll
            for (int j = 0; j < 8; ++j) {
                float f = (xx == 0 || xx == XH - 1) ? 0.f : tile[(c0 + j) * 65 + (xx - 1)];
                v[j] = (short)f2bf(f);
            }
            *reinterpret_cast<s16x8*>(dst + ee * 8) = v;
        }
    } else {
        const int blk = blk0 - XH * 16;    // ks*4 + wv
        const int ks = blk >> 2, wv = blk & 3;
        unsigned short outv[16];
        #pragma unroll
        for (int i = 0; i < 16; ++i) {
            int e = tid * 16 + i;          // e = r*512 + lane*8 + j
            int r = e >> 9;
            int lane = (e >> 3) & 63;
            int j = e & 7;
            int col = wv * 16 + (lane & 15);
            int fp = (lane >> 4) * 8 + ks * 32 + j;
            int tap = fp >> 6, c = fp & 63;
            outv[i] = f2bf(basek[((size_t)r * NF + c * 9 + tap) * NOUT + col]);
        }
        unsigned short* dst = basekF + (size_t)blk * 4096 + tid * 16;
        #pragma unroll
        for (int i = 0; i < 16; ++i) dst[i] = outv[i];
    }
}

// ---------------------------------------------------------------------------
// k_centers: per-(b,k) order-preserving pixel list + slot map + counts +
// cluster centers + (fused) the two MLPs -> lr[bk][8], biasrows[bk][64].
// Gather vectorized: lane = (pixel-group pg = lane>>4, channel-quad cq),
// s16x4 loads (512B/wave-instr), 4 pixels per wave-iter; shfl_xor(16/32)
// cross-lane finish. grid 256 (k*16+b), 576 thr.
// ---------------------------------------------------------------------------
extern "C" __global__ __launch_bounds__(576)
void k_centers(const unsigned short* __restrict__ xcl, const int* __restrict__ labels,
               const float* __restrict__ lw1, const float* __restrict__ lb1,
               const float* __restrict__ lw2, const float* __restrict__ lb2,
               const float* __restrict__ lw3, const float* __restrict__ lb3,
               const float* __restrict__ bw1, const float* __restrict__ bb1,
               const float* __restrict__ bw2, const float* __restrict__ bb2,
               unsigned short* __restrict__ lists, unsigned short* __restrict__ slotmap,
               int* __restrict__ counts,
               float* __restrict__ lrout, float* __restrict__ biasrows)
{
    const int bk = blockIdx.x;
    const int b = bk & 15, k = bk >> 4;
    __shared__ unsigned short list[NPIX];   // 8 KB
    __shared__ int wcnt[9];
    __shared__ float cbuf[NF];              // centers, feature order c*9+tap
    __shared__ float p1[8][NMLP], pb[8][NMLP];
    __shared__ float h1[NMLP], h2[NMLP], hb[NMLP];
    const int tid = threadIdx.x;
    const int lane = tid & 63, wv = tid >> 6;
    const int* lab = labels + b * NPIX;

    // ---- order-preserving compaction
    int total = 0;
    for (int base = 0; base < NPIX; base += 576) {
        int n = base + tid;
        bool pred = (n < NPIX) && (lab[n] == k);
        unsigned long long m = __ballot(pred);
        if (lane == 0) wcnt[wv] = __popcll(m);
        int pre = __popcll(m & ((1ull << lane) - 1ull));
        __syncthreads();
        int wbase = total;
        for (int i = 0; i < wv; ++i) wbase += wcnt[i];
        int nt = total;
        for (int i = 0; i < 9; ++i) nt += wcnt[i];
        if (pred) {
            int slot = wbase + pre;
            list[slot] = (unsigned short)n;
            slotmap[b * NPIX + n] = (unsigned short)slot;
        }
        total = nt;
        __syncthreads();
    }
    const int cnt = total;
    unsigned short* gl = lists + bk * NPIX;
    for (int i = tid; i < cnt; i += 576) gl[i] = list[i];
    if (tid == 0) counts[bk] = cnt;

    // ---- segmented mean gather: wave = tap; lane = (pg, cq)
    const int tap = wv;                              // 0..8
    const int pg = lane >> 4, cq = lane & 15;        // 4 pixel-groups x 16 ch-quads
    const int dy = tap / 3, dx = tap - dy * 3;       // halo offsets 0..2
    const unsigned short* xb = xcl + (size_t)b * (XH * XH * 64);
    float s0 = 0.f, s1 = 0.f, s2 = 0.f, s3 = 0.f;
    #pragma unroll 2
    for (int i = pg; i < cnt; i += 4) {
        int n = list[i];
        const unsigned short* pr = xb + ((((n >> 6) + dy) * XH) + (n & 63) + dx) * 64 + cq * 4;
        s16x4 vv = *reinterpret_cast<const s16x4*>(pr);
        s0 += bf2f((unsigned short)vv[0]);
        s1 += bf2f((unsigned short)vv[1]);
        s2 += bf2f((unsigned short)vv[2]);
        s3 += bf2f((unsigned short)vv[3]);
    }
    s0 += __shfl_xor(s0, 16); s0 += __shfl_xor(s0, 32);
    s1 += __shfl_xor(s1, 16); s1 += __shfl_xor(s1, 32);
    s2 += __shfl_xor(s2, 16); s2 += __shfl_xor(s2, 32);
    s3 += __shfl_xor(s3, 16); s3 += __shfl_xor(s3, 32);
    const float inv = 1.f / ((float)cnt + 1e-6f);
    if (pg == 0) {
        cbuf[(cq * 4 + 0) * 9 + tap] = s0 * inv;
        cbuf[(cq * 4 + 1) * 9 + tap] = s1 * inv;
        cbuf[(cq * 4 + 2) * 9 + tap] = s2 * inv;
        cbuf[(cq * 4 + 3) * 9 + tap] = s3 * inv;
    }
    __syncthreads();

    // ---- fused MLPs (tid < 256 active; barriers block-wide)
    if (tid < 256) {   // layer-1 of both MLPs: j = out unit, ch = feature chunk
        const int j = tid & 31, ch = tid >> 5;       // 8 chunks x 72 feats
        float a1 = 0.f, a2 = 0.f;
        for (int i = 0; i < 72; ++i) {
            int f = ch * 72 + i;
            float cv = cbuf[f];
            a1 += cv * lw1[f * NMLP + j];
            a2 += cv * bw1[f * NMLP + j];
        }
        p1[ch][j] = a1; pb[ch][j] = a2;
    }
    __syncthreads();
    if (tid < NMLP) {
        float a = lb1[tid];
        for (int i = 0; i < 8; ++i) a += p1[i][tid];
        h1[tid] = fmaxf(a, 0.f);
    } else if (tid < 2 * NMLP) {
        int j = tid - NMLP;
        float a = bb1[j];
        for (int i = 0; i < 8; ++i) a += pb[i][j];
        hb[j] = fmaxf(a, 0.f);
    }
    __syncthreads();
    if (tid < NMLP) {
        float a = lb2[tid];
        for (int i = 0; i < NMLP; ++i) a += h1[i] * lw2[i * NMLP + tid];
        h2[tid] = fmaxf(a, 0.f);
    } else if (tid >= 64 && tid < 128) {
        int o = tid - 64;
        float a = bb2[o];
        for (int i = 0; i < NMLP; ++i) a += hb[i] * bw2[i * NOUT + o];
        biasrows[bk * NOUT + o] = a;
    }
    __syncthreads();
    if (tid < NRANK) {
        float a = lb3[tid];
        for (int i = 0; i < NMLP; ++i) a += h2[i] * lw3[i * NRANK + tid];
        lrout[bk * NRANK + tid] = a;
    }
}

// ---------------------------------------------------------------------------
// k_main: gathered GEMM. grid 1024 = 4 splits x 256 (b,k); 256 thr.
// W-build ks-loop FULLY unrolled (R7 lesson: partial unroll -> bfr scratch
// spill, 320 B/thread). Coalesced basekF loads. Prefix computed in-kernel.
// Output compact bf16 outc[b][prefix+slot][o].
// ---------------------------------------------------------------------------
extern "C" __global__ __launch_bounds__(256)
void k_main(const unsigned short* __restrict__ xcl, const unsigned short* __restrict__ lists,
            const int* __restrict__ counts, const unsigned short* __restrict__ basekF,
            const float* __restrict__ lr, const float* __restrict__ biasrows,
            unsigned short* __restrict__ outc)
{
    const int blk = blockIdx.x;
    const int bk = blk & 255, split = blk >> 8;      // 0..3
    const int b = bk & 15, k = bk >> 4;
    const int tid = threadIdx.x;
    const int lane = tid & 63, wv = tid >> 6;
    const int quad = lane >> 4, l16 = lane & 15;
    const int cnt = counts[bk];
    int prefix = 0;
    for (int kk = 0; kk < k; ++kk) prefix += counts[kk * 16 + b];

    __shared__ __align__(16) unsigned short albuf[32 * 584];  // 36.5 KB
    __shared__ float biasl[NOUT];

    if (tid < NOUT) biasl[tid] = biasrows[bk * NOUT + tid];

    // ---- W-build: wave wv owns cols o = wv*16 + l16; k-slices quad*8..+7.
    const int col = wv * 16 + l16;
    float l8[NRANK];
    #pragma unroll
    for (int r = 0; r < NRANK; ++r) l8[r] = lr[bk * NRANK + r];
    const unsigned short* wb = basekF + (size_t)wv * 4096 + lane * 8;
    s16x8 bfr[18];
    #pragma unroll
    for (int ks = 0; ks < 18; ++ks) {
        const unsigned short* wk = wb + (size_t)ks * 16384;
        float w[8] = {0.f, 0.f, 0.f, 0.f, 0.f, 0.f, 0.f, 0.f};
        #pragma unroll
        for (int r = 0; r < NRANK; ++r) {
            s16x8 bv = *reinterpret_cast<const s16x8*>(wk + r * 512);
            #pragma unroll
            for (int j = 0; j < 8; ++j)
                w[j] += l8[r] * bf2f((unsigned short)bv[j]);
        }
        s16x8 f;
        #pragma unroll
        for (int j = 0; j < 8; ++j) f[j] = (short)f2bf(w[j]);
        bfr[ks] = f;
    }

    const unsigned short* xb = xcl + (size_t)b * (XH * XH * 64);
    const unsigned short* gl = lists + bk * NPIX;
    const int p = tid >> 3, part = tid & 7;      // staging role: pixel, 16B part
    const int ntile = (cnt + 31) >> 5;

    for (int t = split; t < ntile; t += 4) {
        // stage current tile (regs short-lived: load -> ds_write)
        int slot = (t << 5) + p;
        int n = (slot < cnt) ? (int)gl[slot] : 0;
        const unsigned short* xrow = xb + (((n >> 6) * XH) + (n & 63)) * 64 + part * 8;
        unsigned short* arow = albuf + p * 584 + part * 8;
        #pragma unroll
        for (int tap = 0; tap < 9; ++tap) {
            int dy = tap / 3, dx = tap - dy * 3;
            *reinterpret_cast<s16x8*>(arow + tap * 64) =
                *reinterpret_cast<const s16x8*>(xrow + (dy * XH + dx) * 64);
        }
        __syncthreads();

        f32x4 acc0 = {0.f, 0.f, 0.f, 0.f}, acc1 = {0.f, 0.f, 0.f, 0.f};
        const unsigned short* ar0 = albuf + l16 * 584 + quad * 8;
        const unsigned short* ar1 = ar0 + 16 * 584;
        #pragma unroll
        for (int ks = 0; ks < 18; ++ks) {
            s16x8 a0 = *reinterpret_cast<const s16x8*>(ar0 + ks * 32);
            s16x8 a1 = *reinterpret_cast<const s16x8*>(ar1 + ks * 32);
            acc0 = __builtin_amdgcn_mfma_f32_16x16x32_bf16(a0, bfr[ks], acc0, 0, 0, 0);
            acc1 = __builtin_amdgcn_mfma_f32_16x16x32_bf16(a1, bfr[ks], acc1, 0, 0, 0);
        }
        __syncthreads();

        // D: col = l16 (-> o), row = quad*4 + reg (-> slot)
        float bb = biasl[col];
        unsigned short* ob = outc + ((size_t)b * NPIX + prefix) * 64;
        #pragma unroll
        for (int r = 0; r < 4; ++r) {
            int s0 = (t << 5) + quad * 4 + r;
            if (s0 < cnt) ob[(size_t)s0 * 64 + col] = f2bf(acc0[r] + bb);
            int s1 = s0 + 16;
            if (s1 < cnt) ob[(size_t)s1 * 64 + col] = f2bf(acc1[r] + bb);
        }
    }
}

// ---------------------------------------------------------------------------
// k_scatter: outc bf16 [b][ptr][o] -> out f32 [b][o][n].
// Gather: 8 lanes per 128B outc row (8 segments/instr). LDS transpose with
// stride-68 u16 rows (2-way bank alias = free). Coalesced f32 stores.
// grid 256 = chunk*16 + b, 256 thr.
// ---------------------------------------------------------------------------
extern "C" __global__ __launch_bounds__(256)
void k_scatter(const int* __restrict__ labels, const unsigned short* __restrict__ slotmap,
               const int* __restrict__ counts, const unsigned short* __restrict__ outc,
               float* __restrict__ out)
{
    const int blk = blockIdx.x;
    const int b = blk & 15, chunk = blk >> 4;
    const int tid = threadIdx.x;
    __shared__ int pref[KC];
    __shared__ int sptr[256];
    __shared__ unsigned short tile[256 * 68];   // 34.8 KB
    if (tid < KC) {
        int s = 0;
        for (int kk = 0; kk < tid; ++kk) s += counts[kk * 16 + b];
        pref[tid] = s;
    }
    __syncthreads();
    const int n0 = chunk * 256;
    {
        int n = n0 + tid;
        int kk = labels[b * NPIX + n];
        sptr[tid] = pref[kk] + (int)slotmap[b * NPIX + n];
    }
    __syncthreads();
    const int pixb = tid >> 3, part = tid & 7;
    #pragma unroll
    for (int pass = 0; pass < 8; ++pass) {
        int pix = pass * 32 + pixb;
        int ptr = sptr[pix];
        s16x8 vv = *reinterpret_cast<const s16x8*>(
            outc + ((size_t)b * NPIX + ptr) * 64 + part * 8);
        s16x4 lo = {vv[0], vv[1], vv[2], vv[3]};
        s16x4 hi = {vv[4], vv[5], vv[6], vv[7]};
        *reinterpret_cast<s16x4*>(&tile[pix * 68 + part * 8]) = lo;     // 8B aligned
        *reinterpret_cast<s16x4*>(&tile[pix * 68 + part * 8 + 4]) = hi;
    }
    __syncthreads();
    float* ob = out + (size_t)b * NOUT * NPIX + n0 + tid;
    #pragma unroll
    for (int o2 = 0; o2 < 32; ++o2) {
        uint32_t pair = *reinterpret_cast<const uint32_t*>(&tile[tid * 68 + o2 * 2]);
        ob[(size_t)(2 * o2) * NPIX]     = bf2f((unsigned short)(pair & 0xffffu));
        ob[(size_t)(2 * o2 + 1) * NPIX] = bf2f((unsigned short)(pair >> 16));
    }
}

// ---------------------------------------------------------------------------
// Workspace layout — TOTAL 20,792,320 B (< 21,627,904 B proven safe):
//   lists    @ 0         : 256*4096 u16      = 2,097,152
//   counts   @ 2097152   : 256 i32           = 1,024
//   (gap     @ 2098176   : 589,824 — unused, was centers)
//   biasrows @ 2688000   : 256*64 f32        = 65,536
//   lr       @ 2753536   : 256*8 f32         = 8,192
//   basekF   @ 2761728   : 72*4096 bf16      = 589,824
//   slotmap  @ 3351552   : 16*4096 u16       = 131,072
//   xcl      @ 3482624   : 16*66*66*64 bf16  = 8,921,088
//   outc     @ 12403712  : 16*4096*64 bf16   = 8,388,608
// ---------------------------------------------------------------------------
extern "C" void kernel_launch(void* const* d_in, const int* in_sizes, int n_in,
                              void* d_out, int out_size, void* d_ws, size_t ws_size,
                              hipStream_t stream)
{
    const float* x      = (const float*)d_in[0];
    const int*   labels = (const int*)d_in[1];
    const float* lw1    = (const float*)d_in[2];
    const float* lb1    = (const float*)d_in[3];
    const float* lw2    = (const float*)d_in[4];
    const float* lb2    = (const float*)d_in[5];
    const float* lw3    = (const float*)d_in[6];
    const float* lb3    = (const float*)d_in[7];
    const float* basek  = (const float*)d_in[8];
    const float* bw1    = (const float*)d_in[9];
    const float* bb1    = (const float*)d_in[10];
    const float* bw2    = (const float*)d_in[11];
    const float* bb2    = (const float*)d_in[12];
    float* out = (float*)d_out;

    char* ws = (char*)d_ws;
    unsigned short* lists   = (unsigned short*)(ws);
    int*            counts  = (int*)(ws + 2097152);
    float*          biasrows= (float*)(ws + 2688000);
    float*          lr      = (float*)(ws + 2753536);
    unsigned short* basekF  = (unsigned short*)(ws + 2761728);
    unsigned short* slotmap = (unsigned short*)(ws + 3351552);
    unsigned short* xcl     = (unsigned short*)(ws + 3482624);
    unsigned short* outc    = (unsigned short*)(ws + 12403712);

    k_prep_all<<<XH * 16 + 72, 256, 0, stream>>>(x, basek, xcl, basekF);
    k_centers<<<256, 576, 0, stream>>>(xcl, labels, lw1, lb1, lw2, lb2, lw3, lb3,
                                       bw1, bb1, bw2, bb2,
                                       lists, slotmap, counts, lr, biasrows);
    k_main<<<1024, 256, 0, stream>>>(xcl, lists, counts, basekF, lr, biasrows, outc);
    k_scatter<<<256, 256, 0, stream>>>(labels, slotmap, counts, outc, out);
}

// Round 9
// 147.130 us; speedup vs baseline: 1.3448x; 1.0592x over previous
//
#include <hip/hip_runtime.h>
#include <stdint.h>
#include <stddef.h>

// Problem constants
#define NB   16
#define NC   64
#define NH   64
#define NW   64
#define KC   16
#define NOUT 64
#define NRANK 8
#define NMLP 32
#define NF   576      // C*3*3
#define NPIX 4096     // H*W
#define XH   66       // halo height/width for channel-last copy

typedef short s16x8 __attribute__((ext_vector_type(8)));
typedef short s16x4 __attribute__((ext_vector_type(4)));
typedef float f32x4 __attribute__((ext_vector_type(4)));

__device__ __forceinline__ unsigned short f2bf(float x) {
    union { float f; uint32_t u; } v; v.f = x;
    uint32_t r = v.u + 0x7FFFu + ((v.u >> 16) & 1u);   // RTNE
    return (unsigned short)(r >> 16);
}
__device__ __forceinline__ float bf2f(unsigned short u) {
    union { uint32_t u; float f; } v; v.u = ((uint32_t)u) << 16;
    return v.f;
}

// ---------------------------------------------------------------------------
// k_prep_all: fused input prep.
//  blocks [0, 1056): x [B][C][H][W] f32 -> xcl [B][66][66][64] bf16
//    channel-last with zero halo; LDS transpose; s16x8 (16B) stores.
//  blocks [1056, 1128): basek [R][F][O] -> basekF bf16 in the per-lane
//    W-expansion order (1024B contiguous per wave load).
// ---------------------------------------------------------------------------
extern "C" __global__ __launch_bounds__(256)
void k_prep_all(const float* __restrict__ x, const float* __restrict__ basek,
                unsigned short* __restrict__ xcl, unsigned short* __restrict__ basekF)
{
    __shared__ float tile[64 * 65];
    const int blk0 = blockIdx.x;
    const int tid = threadIdx.x;
    if (blk0 < XH * 16) {
        const int b = blk0 & 15, yy = blk0 >> 4;
        unsigned short* dst = xcl + ((size_t)(b * XH + yy) * XH) * 64;
        if (yy == 0 || yy == XH - 1) {
            for (int e = tid; e < XH * 64; e += 256) dst[e] = 0;
            return;
        }
        const int y = yy - 1;
        const float* src = x + (size_t)b * NC * (NH * NW) + y * NW;
        #pragma unroll
        for (int rr = 0; rr < 16; ++rr) {
            int c = rr * 4 + (tid >> 6);
            int xx = tid & 63;
            tile[c * 65 + xx] = src[(size_t)c * (NH * NW) + xx];
        }
        __syncthreads();
        // 66*64 u16 = 528 chunks of 8; each chunk one row xx, channels c0..c0+7
        for (int ee = tid; ee < 528; ee += 256) {
            int xx = ee >> 3;
            int c0 = (ee & 7) * 8;
            s16x8 v;
            #pragma unroll
            for (int j = 0; j < 8; ++j) {
                float f = (xx == 0 || xx == XH - 1) ? 0.f : tile[(c0 + j) * 65 + (xx - 1)];
                v[j] = (short)f2bf(f);
            }
            *reinterpret_cast<s16x8*>(dst + ee * 8) = v;
        }
    } else {
        const int blk = blk0 - XH * 16;    // ks*4 + wv
        const int ks = blk >> 2, wv = blk & 3;
        unsigned short outv[16];
        #pragma unroll
        for (int i = 0; i < 16; ++i) {
            int e = tid * 16 + i;          // e = r*512 + lane*8 + j
            int r = e >> 9;
            int lane = (e >> 3) & 63;
            int j = e & 7;
            int col = wv * 16 + (lane & 15);
            int fp = (lane >> 4) * 8 + ks * 32 + j;
            int tap = fp >> 6, c = fp & 63;
            outv[i] = f2bf(basek[((size_t)r * NF + c * 9 + tap) * NOUT + col]);
        }
        unsigned short* dst = basekF + (size_t)blk * 4096 + tid * 16;
        #pragma unroll
        for (int i = 0; i < 16; ++i) dst[i] = outv[i];
    }
}

// ---------------------------------------------------------------------------
// k_centers: per-(b,k) pixel list (barrier-free ballot+LDS-atomic compaction;
// slot order arbitrary but consistent) + slot map + counts + cluster centers
// (vectorized gather) + fused MLPs -> biasrows + fused W-expansion ->
// wt[bk][ks][t][8] bf16 in exactly the order k_main loads (tid-coalesced).
// grid 256 (k*16+b), 576 thr.
// ---------------------------------------------------------------------------
extern "C" __global__ __launch_bounds__(576)
void k_centers(const unsigned short* __restrict__ xcl, const int* __restrict__ labels,
               const float* __restrict__ lw1, const float* __restrict__ lb1,
               const float* __restrict__ lw2, const float* __restrict__ lb2,
               const float* __restrict__ lw3, const float* __restrict__ lb3,
               const float* __restrict__ bw1, const float* __restrict__ bb1,
               const float* __restrict__ bw2, const float* __restrict__ bb2,
               const unsigned short* __restrict__ basekF,
               unsigned short* __restrict__ lists, unsigned short* __restrict__ slotmap,
               int* __restrict__ counts, float* __restrict__ biasrows,
               unsigned short* __restrict__ wt)
{
    const int bk = blockIdx.x;
    const int b = bk & 15, k = bk >> 4;
    __shared__ unsigned short list[NPIX];   // 8 KB
    __shared__ int cntr;
    __shared__ float cbuf[NF];              // centers, feature order c*9+tap
    __shared__ float p1[8][NMLP], pb[8][NMLP];
    __shared__ float h1[NMLP], h2[NMLP], hb[NMLP], lrs[NRANK];
    const int tid = threadIdx.x;
    const int lane = tid & 63, wv = tid >> 6;
    const int* lab = labels + b * NPIX;

    if (tid == 0) cntr = 0;
    __syncthreads();

    // ---- compaction (no ordering requirement): ballot + LDS atomicAdd
    for (int base = 0; base < NPIX; base += 576) {
        int n = base + tid;
        bool pred = (n < NPIX) && (lab[n] == k);
        unsigned long long m = __ballot(pred);
        int pre = __popcll(m & ((1ull << lane) - 1ull));
        int wb = 0;
        if (lane == 0) wb = atomicAdd(&cntr, __popcll(m));
        wb = __shfl(wb, 0);
        if (pred) {
            int slot = wb + pre;
            list[slot] = (unsigned short)n;
            slotmap[b * NPIX + n] = (unsigned short)slot;
        }
    }
    __syncthreads();
    const int cnt = cntr;
    unsigned short* gl = lists + bk * NPIX;
    for (int i = tid; i < cnt; i += 576) gl[i] = list[i];
    if (tid == 0) counts[bk] = cnt;

    // ---- segmented mean gather: wave = tap; lane = (pg, cq)
    const int tap = wv;                              // 0..8
    const int pg = lane >> 4, cq = lane & 15;        // 4 pixel-groups x 16 ch-quads
    const int dy = tap / 3, dx = tap - dy * 3;       // halo offsets 0..2
    const unsigned short* xb = xcl + (size_t)b * (XH * XH * 64);
    float s0 = 0.f, s1 = 0.f, s2 = 0.f, s3 = 0.f;
    #pragma unroll 2
    for (int i = pg; i < cnt; i += 4) {
        int n = list[i];
        const unsigned short* pr = xb + ((((n >> 6) + dy) * XH) + (n & 63) + dx) * 64 + cq * 4;
        s16x4 vv = *reinterpret_cast<const s16x4*>(pr);
        s0 += bf2f((unsigned short)vv[0]);
        s1 += bf2f((unsigned short)vv[1]);
        s2 += bf2f((unsigned short)vv[2]);
        s3 += bf2f((unsigned short)vv[3]);
    }
    s0 += __shfl_xor(s0, 16); s0 += __shfl_xor(s0, 32);
    s1 += __shfl_xor(s1, 16); s1 += __shfl_xor(s1, 32);
    s2 += __shfl_xor(s2, 16); s2 += __shfl_xor(s2, 32);
    s3 += __shfl_xor(s3, 16); s3 += __shfl_xor(s3, 32);
    const float inv = 1.f / ((float)cnt + 1e-6f);
    if (pg == 0) {
        cbuf[(cq * 4 + 0) * 9 + tap] = s0 * inv;
        cbuf[(cq * 4 + 1) * 9 + tap] = s1 * inv;
        cbuf[(cq * 4 + 2) * 9 + tap] = s2 * inv;
        cbuf[(cq * 4 + 3) * 9 + tap] = s3 * inv;
    }
    __syncthreads();

    // ---- fused MLPs (tid < 256 active; barriers block-wide)
    if (tid < 256) {   // layer-1 of both MLPs
        const int j = tid & 31, ch = tid >> 5;       // 8 chunks x 72 feats
        float a1 = 0.f, a2 = 0.f;
        for (int i = 0; i < 72; ++i) {
            int f = ch * 72 + i;
            float cv = cbuf[f];
            a1 += cv * lw1[f * NMLP + j];
            a2 += cv * bw1[f * NMLP + j];
        }
        p1[ch][j] = a1; pb[ch][j] = a2;
    }
    __syncthreads();
    if (tid < NMLP) {
        float a = lb1[tid];
        for (int i = 0; i < 8; ++i) a += p1[i][tid];
        h1[tid] = fmaxf(a, 0.f);
    } else if (tid < 2 * NMLP) {
        int j = tid - NMLP;
        float a = bb1[j];
        for (int i = 0; i < 8; ++i) a += pb[i][j];
        hb[j] = fmaxf(a, 0.f);
    }
    __syncthreads();
    if (tid < NMLP) {
        float a = lb2[tid];
        for (int i = 0; i < NMLP; ++i) a += h1[i] * lw2[i * NMLP + tid];
        h2[tid] = fmaxf(a, 0.f);
    } else if (tid >= 64 && tid < 128) {
        int o = tid - 64;
        float a = bb2[o];
        for (int i = 0; i < NMLP; ++i) a += hb[i] * bw2[i * NOUT + o];
        biasrows[bk * NOUT + o] = a;
    }
    __syncthreads();
    if (tid < NRANK) {
        float a = lb3[tid];
        for (int i = 0; i < NMLP; ++i) a += h2[i] * lw3[i * NRANK + tid];
        lrs[tid] = a;
    }
    __syncthreads();

    // ---- fused W-expansion: wt[bk][ks][t][8] = sum_r lrs[r]*basekF[ks][wv(t)][r][lane(t)][8]
    // thread i handles m = q*576 + i, m = ks*256 + t  (coalesced loads+stores)
    float l8[NRANK];
    #pragma unroll
    for (int r = 0; r < NRANK; ++r) l8[r] = lrs[r];
    unsigned short* wtg = wt + (size_t)bk * (18 * 2048);
    #pragma unroll 1
    for (int q = 0; q < 8; ++q) {
        int m = q * 576 + tid;             // 0..4607
        int ks = m >> 8, t = m & 255;
        const unsigned short* src = basekF
            + ((size_t)(ks * 4 + (t >> 6)) * 8) * 512 + (t & 63) * 8;
        float w[8] = {0.f, 0.f, 0.f, 0.f, 0.f, 0.f, 0.f, 0.f};
        #pragma unroll
        for (int r = 0; r < NRANK; ++r) {
            s16x8 bv = *reinterpret_cast<const s16x8*>(src + r * 512);
            #pragma unroll
            for (int j = 0; j < 8; ++j)
                w[j] += l8[r] * bf2f((unsigned short)bv[j]);
        }
        s16x8 f;
        #pragma unroll
        for (int j = 0; j < 8; ++j) f[j] = (short)f2bf(w[j]);
        *reinterpret_cast<s16x8*>(wtg + ks * 2048 + t * 8) = f;
    }
}

// ---------------------------------------------------------------------------
// k_main: gathered GEMM. grid 1024 = 4 splits x 256 (b,k); 256 thr.
// B-fragments: 18 coalesced 1KB wave-loads from precomputed wt (R9: W-build
// hoisted to k_centers; was 604 MB of L2 traffic in-kernel). Full unroll ->
// constant indices -> registers (R7 scratch-spill lesson).
// Output compact bf16 outc[b][prefix+slot][o].
// ---------------------------------------------------------------------------
extern "C" __global__ __launch_bounds__(256)
void k_main(const unsigned short* __restrict__ xcl, const unsigned short* __restrict__ lists,
            const int* __restrict__ counts, const unsigned short* __restrict__ wt,
            const float* __restrict__ biasrows, unsigned short* __restrict__ outc)
{
    const int blk = blockIdx.x;
    const int bk = blk & 255, split = blk >> 8;      // 0..3
    const int b = bk & 15, k = bk >> 4;
    const int tid = threadIdx.x;
    const int lane = tid & 63, wv = tid >> 6;
    const int quad = lane >> 4, l16 = lane & 15;
    const int cnt = counts[bk];
    int prefix = 0;
    for (int kk = 0; kk < k; ++kk) prefix += counts[kk * 16 + b];

    __shared__ __align__(16) unsigned short albuf[32 * 584];  // 36.5 KB
    __shared__ float biasl[NOUT];

    if (tid < NOUT) biasl[tid] = biasrows[bk * NOUT + tid];

    // ---- B-fragment load: wave wv owns cols o = wv*16 + l16; k-slices quad*8..+7
    const int col = wv * 16 + l16;
    const unsigned short* wsrc = wt + (size_t)bk * (18 * 2048) + tid * 8;
    s16x8 bfr[18];
    #pragma unroll
    for (int ks = 0; ks < 18; ++ks)
        bfr[ks] = *reinterpret_cast<const s16x8*>(wsrc + ks * 2048);

    const unsigned short* xb = xcl + (size_t)b * (XH * XH * 64);
    const unsigned short* gl = lists + bk * NPIX;
    const int p = tid >> 3, part = tid & 7;      // staging role: pixel, 16B part
    const int ntile = (cnt + 31) >> 5;

    for (int t = split; t < ntile; t += 4) {
        // stage current tile (regs short-lived: load -> ds_write)
        int slot = (t << 5) + p;
        int n = (slot < cnt) ? (int)gl[slot] : 0;
        const unsigned short* xrow = xb + (((n >> 6) * XH) + (n & 63)) * 64 + part * 8;
        unsigned short* arow = albuf + p * 584 + part * 8;
        #pragma unroll
        for (int tap = 0; tap < 9; ++tap) {
            int dy = tap / 3, dx = tap - dy * 3;
            *reinterpret_cast<s16x8*>(arow + tap * 64) =
                *reinterpret_cast<const s16x8*>(xrow + (dy * XH + dx) * 64);
        }
        __syncthreads();

        f32x4 acc0 = {0.f, 0.f, 0.f, 0.f}, acc1 = {0.f, 0.f, 0.f, 0.f};
        const unsigned short* ar0 = albuf + l16 * 584 + quad * 8;
        const unsigned short* ar1 = ar0 + 16 * 584;
        #pragma unroll
        for (int ks = 0; ks < 18; ++ks) {
            s16x8 a0 = *reinterpret_cast<const s16x8*>(ar0 + ks * 32);
            s16x8 a1 = *reinterpret_cast<const s16x8*>(ar1 + ks * 32);
            acc0 = __builtin_amdgcn_mfma_f32_16x16x32_bf16(a0, bfr[ks], acc0, 0, 0, 0);
            acc1 = __builtin_amdgcn_mfma_f32_16x16x32_bf16(a1, bfr[ks], acc1, 0, 0, 0);
        }
        __syncthreads();

        // D: col = l16 (-> o), row = quad*4 + reg (-> slot)
        float bb = biasl[col];
        unsigned short* ob = outc + ((size_t)b * NPIX + prefix) * 64;
        #pragma unroll
        for (int r = 0; r < 4; ++r) {
            int s0 = (t << 5) + quad * 4 + r;
            if (s0 < cnt) ob[(size_t)s0 * 64 + col] = f2bf(acc0[r] + bb);
            int s1 = s0 + 16;
            if (s1 < cnt) ob[(size_t)s1 * 64 + col] = f2bf(acc1[r] + bb);
        }
    }
}

// ---------------------------------------------------------------------------
// k_scatter: outc bf16 [b][ptr][o] -> out f32 [b][o][n].
// Gather: 8 lanes per 128B outc row. LDS transpose (stride-68 u16 rows).
// Coalesced f32 stores. grid 256 = chunk*16 + b, 256 thr.
// ---------------------------------------------------------------------------
extern "C" __global__ __launch_bounds__(256)
void k_scatter(const int* __restrict__ labels, const unsigned short* __restrict__ slotmap,
               const int* __restrict__ counts, const unsigned short* __restrict__ outc,
               float* __restrict__ out)
{
    const int blk = blockIdx.x;
    const int b = blk & 15, chunk = blk >> 4;
    const int tid = threadIdx.x;
    __shared__ int pref[KC];
    __shared__ int sptr[256];
    __shared__ unsigned short tile[256 * 68];   // 34.8 KB
    if (tid < KC) {
        int s = 0;
        for (int kk = 0; kk < tid; ++kk) s += counts[kk * 16 + b];
        pref[tid] = s;
    }
    __syncthreads();
    const int n0 = chunk * 256;
    {
        int n = n0 + tid;
        int kk = labels[b * NPIX + n];
        sptr[tid] = pref[kk] + (int)slotmap[b * NPIX + n];
    }
    __syncthreads();
    const int pixb = tid >> 3, part = tid & 7;
    #pragma unroll
    for (int pass = 0; pass < 8; ++pass) {
        int pix = pass * 32 + pixb;
        int ptr = sptr[pix];
        s16x8 vv = *reinterpret_cast<const s16x8*>(
            outc + ((size_t)b * NPIX + ptr) * 64 + part * 8);
        s16x4 lo = {vv[0], vv[1], vv[2], vv[3]};
        s16x4 hi = {vv[4], vv[5], vv[6], vv[7]};
        *reinterpret_cast<s16x4*>(&tile[pix * 68 + part * 8]) = lo;     // 8B aligned
        *reinterpret_cast<s16x4*>(&tile[pix * 68 + part * 8 + 4]) = hi;
    }
    __syncthreads();
    float* ob = out + (size_t)b * NOUT * NPIX + n0 + tid;
    #pragma unroll
    for (int o2 = 0; o2 < 32; ++o2) {
        uint32_t pair = *reinterpret_cast<const uint32_t*>(&tile[tid * 68 + o2 * 2]);
        ob[(size_t)(2 * o2) * NPIX]     = bf2f((unsigned short)(pair & 0xffffu));
        ob[(size_t)(2 * o2 + 1) * NPIX] = bf2f((unsigned short)(pair >> 16));
    }
}

// ---------------------------------------------------------------------------
// Workspace layout — TOTAL 39,068,672 B (ws_size ≈ 256 MiB per R8 profile):
//   lists    @ 0         : 256*4096 u16      = 2,097,152
//   counts   @ 2097152   : 256 i32           = 1,024
//   biasrows @ 2098176   : 256*64 f32        = 65,536
//   basekF   @ 2163712   : 72*4096 bf16      = 589,824
//   slotmap  @ 2753536   : 16*4096 u16       = 131,072
//   xcl      @ 2884608   : 16*66*66*64 bf16  = 8,921,088
//   outc     @ 11805696  : 16*4096*64 bf16   = 8,388,608
//   wt       @ 20194304  : 256*18*2048 bf16  = 18,874,368
// ---------------------------------------------------------------------------
extern "C" void kernel_launch(void* const* d_in, const int* in_sizes, int n_in,
                              void* d_out, int out_size, void* d_ws, size_t ws_size,
                              hipStream_t stream)
{
    const float* x      = (const float*)d_in[0];
    const int*   labels = (const int*)d_in[1];
    const float* lw1    = (const float*)d_in[2];
    const float* lb1    = (const float*)d_in[3];
    const float* lw2    = (const float*)d_in[4];
    const float* lb2    = (const float*)d_in[5];
    const float* lw3    = (const float*)d_in[6];
    const float* lb3    = (const float*)d_in[7];
    const float* basek  = (const float*)d_in[8];
    const float* bw1    = (const float*)d_in[9];
    const float* bb1    = (const float*)d_in[10];
    const float* bw2    = (const float*)d_in[11];
    const float* bb2    = (const float*)d_in[12];
    float* out = (float*)d_out;

    char* ws = (char*)d_ws;
    unsigned short* lists   = (unsigned short*)(ws);
    int*            counts  = (int*)(ws + 2097152);
    float*          biasrows= (float*)(ws + 2098176);
    unsigned short* basekF  = (unsigned short*)(ws + 2163712);
    unsigned short* slotmap = (unsigned short*)(ws + 2753536);
    unsigned short* xcl     = (unsigned short*)(ws + 2884608);
    unsigned short* outc    = (unsigned short*)(ws + 11805696);
    unsigned short* wt      = (unsigned short*)(ws + 20194304);

    k_prep_all<<<XH * 16 + 72, 256, 0, stream>>>(x, basek, xcl, basekF);
    k_centers<<<256, 576, 0, stream>>>(xcl, labels, lw1, lb1, lw2, lb2, lw3, lb3,
                                       bw1, bb1, bw2, bb2, basekF,
                                       lists, slotmap, counts, biasrows, wt);
    k_main<<<1024, 256, 0, stream>>>(xcl, lists, counts, wt, biasrows, outc);
    k_scatter<<<256, 256, 0, stream>>>(labels, slotmap, counts, outc, out);
}